// Round 7
// baseline (194.305 us; speedup 1.0000x reference)
//
#include <hip/hip_runtime.h>
#include <cstdint>

#define NHEAD 12
#define TLEN 2048
#define CDIM 768
#define NSETS 1023   // 512+256+128+64+32+16+8+4+2+1

typedef __attribute__((ext_vector_type(8))) _Float16 half8;
typedef __attribute__((ext_vector_type(2))) __fp16 fp16x2;
typedef __attribute__((ext_vector_type(8))) short short8;   // 8 bf16
typedef __attribute__((ext_vector_type(8))) unsigned short u16x8;
typedef __attribute__((ext_vector_type(4))) float f32x4;

#define SOFTMAX_SCL 0.18033688011112042f   // 0.125 * log2(e)

__device__ __forceinline__ float elu1(float x) { return x > 0.f ? x + 1.f : __expf(x); }

__device__ __forceinline__ unsigned pack2_bf16_trunc(float a, float b) {
    unsigned ua = __float_as_uint(a), ub = __float_as_uint(b);
    return __builtin_amdgcn_perm(ub, ua, 0x07060302);
}
__device__ __forceinline__ unsigned pack2_bf16_rne(float a, float b) {
    unsigned ua = __float_as_uint(a), ub = __float_as_uint(b);
    ua = ua + 0x7fff + ((ua >> 16) & 1);
    ub = ub + 0x7fff + ((ub >> 16) & 1);
    return (ub & 0xffff0000u) | (ua >> 16);
}
__device__ __forceinline__ unsigned short bf16_hi_trunc(float a) {
    return (unsigned short)(__float_as_uint(a) >> 16);
}
__device__ __forceinline__ unsigned short bf16_lo_trunc(float a) {
    unsigned ua = __float_as_uint(a);
    float r = a - __uint_as_float(ua & 0xffff0000u);
    return (unsigned short)(__float_as_uint(r) >> 16);
}
__device__ __forceinline__ unsigned short bf16_rne(float a) {
    unsigned ua = __float_as_uint(a);
    ua = ua + 0x7fff + ((ua >> 16) & 1);
    return (unsigned short)(ua >> 16);
}
__device__ __forceinline__ short8 mk_short8(const unsigned* u) {
    union { unsigned w[4]; short8 s; } x;
    x.w[0] = u[0]; x.w[1] = u[1]; x.w[2] = u[2]; x.w[3] = u[3];
    return x.s;
}
__device__ __forceinline__ short8 as_s8(u16x8 v) {
    union { u16x8 u; short8 s; } x; x.u = v; return x.s;
}
__device__ __forceinline__ void split8_bf16(const float* f, short8& hi, short8& lo) {
    unsigned hp[4], lp[4];
    #pragma unroll
    for (int p = 0; p < 4; ++p) {
        float a = f[2 * p], b = f[2 * p + 1];
        unsigned ua = __float_as_uint(a), ub = __float_as_uint(b);
        hp[p] = __builtin_amdgcn_perm(ub, ua, 0x07060302);
        float ra = a - __uint_as_float(ua & 0xffff0000u);
        float rb = b - __uint_as_float(ub & 0xffff0000u);
        lp[p] = pack2_bf16_trunc(ra, rb);
    }
    hi = mk_short8(hp); lo = mk_short8(lp);
}
__device__ __forceinline__ half8 cvt8_f16(const float* f) {
    union { fp16x2 h2[4]; half8 h8; } u;
    #pragma unroll
    for (int jp = 0; jp < 4; ++jp)
        u.h2[jp] = __builtin_amdgcn_cvt_pkrtz(f[2 * jp], f[2 * jp + 1]);
    return u.h8;
}

// ---------- merged prep: 4x W768 blobs + map-W blob + x f16 frag blob ----------
__global__ __launch_bounds__(256) void prep_all(
    const float* __restrict__ Wq, const float* __restrict__ Wk,
    const float* __restrict__ Wv, const float* __restrict__ Wc4,
    const float* __restrict__ Wks, const float* __restrict__ Wvs,
    const float* __restrict__ x,
    _Float16* __restrict__ blobQKV, _Float16* __restrict__ blobC,
    _Float16* __restrict__ Wblob,
    _Float16* __restrict__ xf)
{
    const int g = blockIdx.x;
    const int tid = threadIdx.x;
    if (g < 9216) {
        const int sel = g / 2304;
        const float* W = sel == 0 ? Wq : (sel == 1 ? Wk : (sel == 2 ? Wv : Wc4));
        _Float16* blob = (sel < 3) ? (blobQKV + (size_t)sel * 589824) : blobC;
        const int idx = (g % 2304) * 256 + tid;
        const int k = idx / 768, n = idx % 768;
        const int i = k >> 5, kl = k & 31;
        const int quad = kl >> 3, j = kl & 7;
        const int nsg = n >> 4, lane15 = n & 15;
        const int lane = quad * 16 + lane15;
        blob[((size_t)(i * 48 + nsg) * 64 + lane) * 8 + j] = (_Float16)W[idx];
    } else if (g < 9216 + 2048) {
        const int idx = (g - 9216) * 256 + tid;
        const int kk = idx >> 7, n = idx & 127;
        float f = (n < 64) ? Wks[(size_t)kk * 64 + n] : Wvs[(size_t)kk * 64 + (n - 64)];
        const int i = kk >> 6, kl = kk & 63;
        const int ks = kl >> 5, quad = (kl >> 3) & 3, j = kl & 7;
        const int nsg = n >> 4, lane15 = n & 15;
        const int lane = quad * 16 + lane15;
        const size_t off = ((size_t)(((i * 2 + ks) * 8 + nsg)) * 64 + lane) * 8 + j;
        Wblob[off] = (_Float16)f;
    } else {
        // x (2048x768) -> single-f16 fragment-major blob
        const int p = (g - 11264) * 256 + tid;   // one half8 per thread
        const int lane = p & 63, frag = p >> 6;
        const int m16 = frag / 24, k32 = frag - m16 * 24;
        const int row = m16 * 16 + (lane & 15);
        const int col = k32 * 32 + (lane >> 4) * 8;
        float f[8];
        *(float4*)&f[0] = *(const float4*)&x[(size_t)row * CDIM + col];
        *(float4*)&f[4] = *(const float4*)&x[(size_t)row * CDIM + col + 4];
        *(half8*)&xf[(size_t)p * 8] = cvt8_f16(f);
    }
}

// ---------- fragment-direct MFMA GEMM, single-f16 A, BK=64 pipeline ----------
template<int QKV>
__global__ __launch_bounds__(256, 3) void gemm_frag(
    const _Float16* __restrict__ Af,
    const _Float16* __restrict__ Bblobs, const float* __restrict__ bias,
    float* __restrict__ outq, unsigned* __restrict__ kdup,
    _Float16* __restrict__ v16)
{
    const int nbx = QKV ? 18 : 12;
    const int cpx = QKV ? 72 : 48;         // blocks per XCD = nwg/8
    int bid = blockIdx.x;
    bid = (bid & 7) * cpx + (bid >> 3);    // bijective XCD swizzle (nwg % 8 == 0)
    const int by  = bid / nbx;             // row-block (64 rows)
    const int bxg = bid % nbx;
    const int which = QKV ? bxg / 6 : 0;
    const int bxm   = QKV ? bxg % 6 : bxg;
    const half8* __restrict__ Bc = (const half8*)(Bblobs + (size_t)which * 589824);

    const int tid = threadIdx.x;
    const int wave = tid >> 6, lane = tid & 63;
    const int lane15 = lane & 15, quad = lane >> 4;
    const int m16b = by * 4;
    const int nsg0 = QKV ? (bxm * 8 + wave * 2) : (bxm * 4 + wave);

    const half8* __restrict__ Ah = (const half8*)Af;

    f32x4 acc[4][2];
    #pragma unroll
    for (int ms = 0; ms < 4; ++ms) {
        acc[ms][0] = (f32x4){0.f, 0.f, 0.f, 0.f};
        acc[ms][1] = (f32x4){0.f, 0.f, 0.f, 0.f};
    }

    const size_t aBase = ((size_t)m16b * 24) * 64 + lane;   // half8 units
    const size_t bBase = (size_t)nsg0 * 64 + lane;

    half8 aC[2][4], bC[2][2], aN[2][4], bN[2][2];
    auto loadA = [&](half8 (*dst)[4], int k32a) {
        #pragma unroll
        for (int u = 0; u < 2; ++u)
            #pragma unroll
            for (int ms = 0; ms < 4; ++ms)
                dst[u][ms] = Ah[aBase + (size_t)(k32a + u) * 64 + (size_t)ms * (24 * 64)];
    };
    auto loadB = [&](half8 (*dst)[2], int k32a) {
        #pragma unroll
        for (int u = 0; u < 2; ++u) {
            const size_t bo = bBase + (size_t)(k32a + u) * (48 * 64);
            dst[u][0] = Bc[bo];
            if (QKV) dst[u][1] = Bc[bo + 64];
        }
    };

    loadA(aC, 0); loadB(bC, 0);
    for (int kk = 0; kk < 12; ++kk) {
        const bool more = (kk + 1) < 12;
        if (more) { loadA(aN, 2 * kk + 2); loadB(bN, 2 * kk + 2); }
        #pragma unroll
        for (int u = 0; u < 2; ++u)
            #pragma unroll
            for (int ms = 0; ms < 4; ++ms) {
                acc[ms][0] = __builtin_amdgcn_mfma_f32_16x16x32_f16(aC[u][ms], bC[u][0], acc[ms][0], 0, 0, 0);
                if (QKV)
                    acc[ms][1] = __builtin_amdgcn_mfma_f32_16x16x32_f16(aC[u][ms], bC[u][1], acc[ms][1], 0, 0, 0);
            }
        if (more) {
            #pragma unroll
            for (int u = 0; u < 2; ++u) {
                bC[u][0] = bN[u][0]; bC[u][1] = bN[u][1];
                #pragma unroll
                for (int ms = 0; ms < 4; ++ms) aC[u][ms] = aN[u][ms];
            }
        }
    }

    const int NSL = QKV ? 2 : 1;
    #pragma unroll
    for (int ms = 0; ms < 4; ++ms)
        #pragma unroll
        for (int nb = 0; nb < 2; ++nb) {
            if (nb >= NSL) break;
            const int coln = (nsg0 + nb) * 16 + lane15;
            #pragma unroll
            for (int r = 0; r < 4; ++r) {
                const int row = m16b * 16 + ms * 16 + quad * 4 + r;
                float vv = acc[ms][nb][r];
                if (!QKV) {
                    outq[(size_t)row * CDIM + coln] = vv + bias[coln];
                } else if (which == 0) {
                    outq[(size_t)row * CDIM + coln] = elu1(vv);
                } else if (which == 1) {
                    float e = elu1(vv);
                    union { fp16x2 h; unsigned u; } cc;
                    cc.h = __builtin_amdgcn_cvt_pkrtz(e, e);
                    kdup[(size_t)row * CDIM + coln] = cc.u;
                } else {
                    union { fp16x2 h; _Float16 f2[2]; } cc;
                    cc.h = __builtin_amdgcn_cvt_pkrtz(vv, vv);
                    v16[(size_t)row * CDIM + coln] = cc.f2[0];
                }
            }
        }
}

// ---------- MFMA mapped features v8 ----------
__global__ __launch_bounds__(256, 2) void map_f16(
    const unsigned* __restrict__ kdup, const _Float16* __restrict__ v16,
    const _Float16* __restrict__ Wblob,
    float* __restrict__ kkv, float* __restrict__ vvv)
{
    __shared__ unsigned kU[64][65];   // half2(k,k) for 64 positions x 64 dims

    const int tid = threadIdx.x;
    const int p0 = blockIdx.x * 64;
    const int wave = tid >> 6, lane = tid & 63;
    const int lane15 = lane & 15, quad = lane >> 4;

    {
        const int row = tid >> 2, cb = (tid & 3) * 16;
        const unsigned* src = &kdup[(size_t)(p0 + row) * 64 + cb];
        uint4 a0 = *(const uint4*)(src + 0);
        uint4 a1 = *(const uint4*)(src + 4);
        uint4 a2 = *(const uint4*)(src + 8);
        uint4 a3 = *(const uint4*)(src + 12);
        *(uint4*)&kU[row][cb + 0]  = a0;
        *(uint4*)&kU[row][cb + 4]  = a1;
        *(uint4*)&kU[row][cb + 8]  = a2;
        *(uint4*)&kU[row][cb + 12] = a3;
    }

    half8 vrh[4][2];
    #pragma unroll
    for (int mh = 0; mh < 4; ++mh) {
        const size_t pbase = (size_t)(p0 + mh * 16 + lane15) * 64;
        #pragma unroll
        for (int ks = 0; ks < 2; ++ks)
            vrh[mh][ks] = *(const half8*)&v16[pbase + ks * 32 + quad * 8];
    }
    __syncthreads();

    const half8* __restrict__ Wc = (const half8*)Wblob;

    f32x4 acc[4][2];
    #pragma unroll
    for (int mh = 0; mh < 4; ++mh)
        #pragma unroll
        for (int nsl = 0; nsl < 2; ++nsl)
            acc[mh][nsl] = (f32x4){0.f, 0.f, 0.f, 0.f};

    half8 b0[2], b1[2], b2[2], b3[2];
    unsigned ka0[4], ka1[4], ka2[4], ka3[4];

    auto loadB = [&](half8* b, int s) {
        b[0] = Wc[(size_t)(s * 8 + 2 * wave) * 64 + lane];
        b[1] = Wc[(size_t)(s * 8 + 2 * wave + 1) * 64 + lane];
    };
    auto loadK = [&](unsigned* ka, int s) {
        const int i = s >> 1;
        #pragma unroll
        for (int mh = 0; mh < 4; ++mh) ka[mh] = kU[mh * 16 + lane15][i];
    };
    auto compute = [&](const half8* b, const unsigned* ka, int s) {
        const int ks = s & 1;
        #pragma unroll
        for (int mh = 0; mh < 4; ++mh) {
            union { unsigned u; fp16x2 h; } ku; ku.u = ka[mh];
            union { fp16x2 h2[4]; half8 h8; } va, ra;
            va.h8 = vrh[mh][ks];
            #pragma unroll
            for (int jp = 0; jp < 4; ++jp) ra.h2[jp] = ku.h * va.h2[jp];
            acc[mh][0] = __builtin_amdgcn_mfma_f32_16x16x32_f16(ra.h8, b[0], acc[mh][0], 0, 0, 0);
            acc[mh][1] = __builtin_amdgcn_mfma_f32_16x16x32_f16(ra.h8, b[1], acc[mh][1], 0, 0, 0);
        }
    };

    loadB(b0, 0); loadB(b1, 1); loadB(b2, 2); loadB(b3, 3);
    loadK(ka0, 0); loadK(ka1, 1); loadK(ka2, 2); loadK(ka3, 3);
    for (int s = 0; s < 128; s += 4) {
        const bool more = (s + 4) < 128;
        compute(b0, ka0, s);
        compute(b1, ka1, s + 1);
        if (more) { loadB(b0, s + 4); loadK(ka0, s + 4); loadB(b1, s + 5); loadK(ka1, s + 5); }
        compute(b2, ka2, s + 2);
        compute(b3, ka3, s + 3);
        if (more) { loadB(b2, s + 6); loadK(ka2, s + 6); loadB(b3, s + 7); loadK(ka3, s + 7); }
    }

    #pragma unroll
    for (int mh = 0; mh < 4; ++mh)
        #pragma unroll
        for (int nsl = 0; nsl < 2; ++nsl) {
            int n128 = (2 * wave + nsl) * 16 + lane15;
            float* dst = (n128 < 64) ? kkv : vvv;
            int col = n128 & 63;
            #pragma unroll
            for (int r = 0; r < 4; ++r) {
                int p = p0 + mh * 16 + quad * 4 + r;
                dst[(size_t)p * 64 + col] = acc[mh][nsl][r];
            }
        }
}

// ---------- set features: write K pre-split bf16 hi/lo + V bf16 RNE ----------
__global__ __launch_bounds__(256) void set_lower(
    const float* __restrict__ kkv, const float* __restrict__ vvv,
    const float* __restrict__ bks, const float* __restrict__ bvs,
    unsigned short* __restrict__ KsetH, unsigned short* __restrict__ KsetL,
    unsigned short* __restrict__ VsetB,
    float* __restrict__ scrK, float* __restrict__ scrV,
    float* __restrict__ Kt, float* __restrict__ Vt)
{
    __shared__ float curK[63][64];
    __shared__ float curV[63][64];
    const int tid = threadIdx.x;
    const int col = tid & 63, grp = tid >> 6;
    const int h = blockIdx.x % NHEAD;
    const int c = blockIdx.x / NHEAD;
    const int t0 = c * 128;
    const float bk = bks[col], bv = bvs[col];

    for (int j = grp; j < 32; j += 4) {
        const size_t rbase = (size_t)(t0 + j * 4) * CDIM + h * 64 + col;
        const float* pk = kkv + rbase;
        const float* pv = vvv + rbase;
        float* ptK = Kt + rbase;
        float* ptV = Vt + rbase;
        float sk = bk, sv = bv;
        #pragma unroll
        for (int u = 0; u < 4; ++u) {
            sk += pk[(size_t)u * CDIM];
            sv += pv[(size_t)u * CDIM];
            ptK[(size_t)u * CDIM] = sk;
            ptV[(size_t)u * CDIM] = sv;
        }
        curK[j][col] = sk - bk; curV[j][col] = sv - bv;
        size_t o = ((size_t)(c * 32 + j) * NHEAD + h) * 64 + col;
        KsetH[o] = bf16_hi_trunc(sk); KsetL[o] = bf16_lo_trunc(sk);
        VsetB[o] = bf16_rne(sv);
    }
    __syncthreads();

    const int LBASE[6] = {0, 32, 48, 56, 60, 62};
    const int GBASE[6] = {0, 512, 768, 896, 960, 992};
    #pragma unroll
    for (int li = 1; li < 6; ++li) {
        const int ns = 32 >> li;
        for (int j = grp; j < ns; j += 4) {
            float sk = curK[LBASE[li - 1] + 2 * j][col] + curK[LBASE[li - 1] + 2 * j + 1][col];
            float sv = curV[LBASE[li - 1] + 2 * j][col] + curV[LBASE[li - 1] + 2 * j + 1][col];
            curK[LBASE[li] + j][col] = sk; curV[LBASE[li] + j][col] = sv;
            size_t o = ((size_t)(GBASE[li] + c * ns + j) * NHEAD + h) * 64 + col;
            float kv_ = sk + bk, vv_ = sv + bv;
            KsetH[o] = bf16_hi_trunc(kv_); KsetL[o] = bf16_lo_trunc(kv_);
            VsetB[o] = bf16_rne(vv_);
        }
        __syncthreads();
    }

    if (grp == 0) {
        scrK[((size_t)h * 16 + c) * 64 + col] = curK[62][col];
        scrV[((size_t)h * 16 + c) * 64 + col] = curV[62][col];
    }
}

__global__ __launch_bounds__(256) void set_upper(
    const float* __restrict__ scrK, const float* __restrict__ scrV,
    const float* __restrict__ bks, const float* __restrict__ bvs,
    unsigned short* __restrict__ KsetH, unsigned short* __restrict__ KsetL,
    unsigned short* __restrict__ VsetB)
{
    __shared__ float cK[15][64], cV[15][64];
    const int h = blockIdx.x;
    const int tid = threadIdx.x, col = tid & 63, grp = tid >> 6;
    const float bk = bks[col], bv = bvs[col];

    for (int j = grp; j < 8; j += 4) {
        float sk = scrK[((size_t)h * 16 + 2 * j) * 64 + col] + scrK[((size_t)h * 16 + 2 * j + 1) * 64 + col];
        float sv = scrV[((size_t)h * 16 + 2 * j) * 64 + col] + scrV[((size_t)h * 16 + 2 * j + 1) * 64 + col];
        cK[j][col] = sk; cV[j][col] = sv;
        size_t o = ((size_t)(1008 + j) * NHEAD + h) * 64 + col;
        float kv_ = sk + bk, vv_ = sv + bv;
        KsetH[o] = bf16_hi_trunc(kv_); KsetL[o] = bf16_lo_trunc(kv_);
        VsetB[o] = bf16_rne(vv_);
    }
    __syncthreads();
    const int LB[4] = {0, 8, 12, 14};
    const int GB[4] = {1008, 1016, 1020, 1022};
    #pragma unroll
    for (int li = 1; li < 4; ++li) {
        const int ns = 8 >> li;
        for (int j = grp; j < ns; j += 4) {
            float sk = cK[LB[li - 1] + 2 * j][col] + cK[LB[li - 1] + 2 * j + 1][col];
            float sv = cV[LB[li - 1] + 2 * j][col] + cV[LB[li - 1] + 2 * j + 1][col];
            cK[LB[li] + j][col] = sk; cV[LB[li] + j][col] = sv;
            size_t o = ((size_t)(GB[li] + j) * NHEAD + h) * 64 + col;
            float kv_ = sk + bk, vv_ = sv + bv;
            KsetH[o] = bf16_hi_trunc(kv_); KsetL[o] = bf16_lo_trunc(kv_);
            VsetB[o] = bf16_rne(vv_);
        }
        __syncthreads();
    }
}

// ---------- MFMA flash attention v7: 64-row Q-tiles (fixed per-tile cost
// amortized over 2x rows; K/V L2 traffic halves), single-buffered sS/sP
// (B2/B1 barrier chain orders the hazards; only vP needs double-buffer),
// guard-free base-2 softmax, pre-split bf16 K/V, f16 fragment output ----------
__global__ __launch_bounds__(256, 2) void attn_mfma(
    const float* __restrict__ qbuf,
    const unsigned short* __restrict__ KsetH, const unsigned short* __restrict__ KsetL,
    const unsigned short* __restrict__ VsetB,
    const float* __restrict__ Ktail, const float* __restrict__ Vtail,
    _Float16* __restrict__ attf)
{
    __shared__ unsigned ssAll[1024];       // sid | (send<<16)
    __shared__ float sS[64][68];           // masked logits (pre-scaled)
    __shared__ unsigned sP[64][40];        // P as bf16 pairs along k
    __shared__ unsigned vP[2][64][40];     // V^T as bf16 pairs along set
    __shared__ float arowS[64];
    __shared__ float alS[64], ptS[64];

    const int tid = threadIdx.x;
    const int b   = 31 - (blockIdx.x / NHEAD);   // heavy blocks dispatched first
    const int h   = blockIdx.x % NHEAD;
    const int T0  = b * 64;
    const int wave = tid >> 6, lane = tid & 63;
    const int lane15 = lane & 15, quad = lane >> 4;

    const int Tend = T0 + 64;
    const int LOFF[10] = {0, 512, 768, 896, 960, 992, 1008, 1016, 1020, 1022};
    int pfx[10], Vtot = 0;
    #pragma unroll
    for (int li = 0; li < 10; ++li) { pfx[li] = Vtot; Vtot += Tend >> (li + 2); }
    const int ntiles = (Vtot + 63) >> 6;

    for (int j = tid; j < 1024; j += 256) {
        unsigned pk = (4095u << 16);       // send=4095 masks all rows; sid=0 harmless
        if (j < Vtot) {
            int li = 0;
            #pragma unroll
            for (int u = 1; u < 10; ++u) if (j >= pfx[u]) li = u;
            int idx = j - pfx[li];
            pk = (unsigned)(LOFF[li] + idx) | ((unsigned)((idx + 1) << (li + 2)) << 16);
        }
        ssAll[j] = pk;
    }

    short8 Qhi[4][2], Qlo[4][2];
    #pragma unroll
    for (int ms = 0; ms < 4; ++ms)
        #pragma unroll
        for (int kt = 0; kt < 2; ++kt) {
            const float* qp = qbuf + ((size_t)(T0 + ms * 16 + lane15) * NHEAD + h) * 64 + kt * 32 + quad * 8;
            float f[8];
            *(float4*)&f[0] = *(const float4*)qp;
            *(float4*)&f[4] = *(const float4*)(qp + 4);
            split8_bf16(f, Qhi[ms][kt], Qlo[ms][kt]);
        }

    __syncthreads();   // ssAll ready

    // per-thread softmax state: thread owns row tid>>2, cols (tid&3)*16..+15
    const int row = tid >> 2, part = tid & 3;
    float mreg = -1e30f, lreg = 0.f;

    f32x4 oacc[4];
    #pragma unroll
    for (int ms = 0; ms < 4; ++ms) oacc[ms] = (f32x4){0.f, 0.f, 0.f, 0.f};

    u16x8 Va, Vb;                  // V bf16: 8 dims of even/odd set
    u16x8 KH[2], KL[2];            // K bf16 hi/lo: dims quad*8..+7, +32
    const int sp = tid >> 3, dd = (tid & 7) * 8;
    auto prefV = [&](int tile) {
        int sa = (int)(ssAll[tile * 64 + 2 * sp] & 0xffffu);
        int sb = (int)(ssAll[tile * 64 + 2 * sp + 1] & 0xffffu);
        Va = *(const u16x8*)(VsetB + ((size_t)sa * NHEAD + h) * 64 + dd);
        Vb = *(const u16x8*)(VsetB + ((size_t)sb * NHEAD + h) * 64 + dd);
    };
    auto prefK = [&](int tile) {
        int sK = (int)(ssAll[tile * 64 + wave * 16 + lane15] & 0xffffu);
        const size_t ko = ((size_t)sK * NHEAD + h) * 64 + quad * 8;
        KH[0] = *(const u16x8*)(KsetH + ko);
        KH[1] = *(const u16x8*)(KsetH + ko + 32);
        KL[0] = *(const u16x8*)(KsetL + ko);
        KL[1] = *(const u16x8*)(KsetL + ko + 32);
    };
    prefV(0); prefK(0);

    for (int tile = 0; tile < ntiles; ++tile) {
        const int c = tile & 1;

        // stage V^T bf16 pairs (pure shift-or)
        #pragma unroll
        for (int i = 0; i < 8; ++i)
            vP[c][dd + i][sp] = (unsigned)Va[i] | ((unsigned)Vb[i] << 16);

        // K fragments: direct reinterpret (pre-split)
        short8 Khi[2] = { as_s8(KH[0]), as_s8(KH[1]) };
        short8 Klo[2] = { as_s8(KL[0]), as_s8(KL[1]) };

        // QK^T 3-term split, 4 row-fragments
        f32x4 lacc[4];
        #pragma unroll
        for (int ms = 0; ms < 4; ++ms) lacc[ms] = (f32x4){0.f, 0.f, 0.f, 0.f};
        #pragma unroll
        for (int kt = 0; kt < 2; ++kt)
            #pragma unroll
            for (int ms = 0; ms < 4; ++ms) {
                lacc[ms] = __builtin_amdgcn_mfma_f32_16x16x32_bf16(Qhi[ms][kt], Khi[kt], lacc[ms], 0, 0, 0);
                lacc[ms] = __builtin_amdgcn_mfma_f32_16x16x32_bf16(Qlo[ms][kt], Khi[kt], lacc[ms], 0, 0, 0);
                lacc[ms] = __builtin_amdgcn_mfma_f32_16x16x32_bf16(Qhi[ms][kt], Klo[kt], lacc[ms], 0, 0, 0);
            }

        // mask + scale (base-2 domain) -> sS  (write ordered after prior
        // softmax reads by B2 of previous iteration)
        {
            const int sendv = (int)(ssAll[tile * 64 + wave * 16 + lane15] >> 16);
            #pragma unroll
            for (int ms = 0; ms < 4; ++ms)
                #pragma unroll
                for (int r = 0; r < 4; ++r) {
                    int qrow = ms * 16 + quad * 4 + r;
                    bool ok = (T0 + qrow + 1) >= sendv;
                    sS[qrow][wave * 16 + lane15] = ok ? lacc[ms][r] * SOFTMAX_SCL : -1e30f;
                }
        }

        // issue prefetch for next tile
        if (tile + 1 < ntiles) { prefV(tile + 1); prefK(tile + 1); }

        __syncthreads();   // B1: sS + vP[c] published; prior-tile PV complete

        // register softmax (base-2, guard-free)
        {
            float4 a0 = *(float4*)&sS[row][part * 16];
            float4 a1 = *(float4*)&sS[row][part * 16 + 4];
            float4 a2 = *(float4*)&sS[row][part * 16 + 8];
            float4 a3 = *(float4*)&sS[row][part * 16 + 12];
            float mx = fmaxf(fmaxf(fmaxf(a0.x, a0.y), fmaxf(a0.z, a0.w)),
                             fmaxf(fmaxf(a1.x, a1.y), fmaxf(a1.z, a1.w)));
            mx = fmaxf(mx, fmaxf(fmaxf(fmaxf(a2.x, a2.y), fmaxf(a2.z, a2.w)),
                                 fmaxf(fmaxf(a3.x, a3.y), fmaxf(a3.z, a3.w))));
            mx = fmaxf(mx, __shfl_xor(mx, 1));
            mx = fmaxf(mx, __shfl_xor(mx, 2));
            float mnew = fmaxf(mreg, mx);
            float al = exp2f(mreg - mnew);
            mreg = mnew;
            float mexp = fmaxf(mnew, -1e28f);
            a0.x = exp2f(a0.x - mexp); a0.y = exp2f(a0.y - mexp);
            a0.z = exp2f(a0.z - mexp); a0.w = exp2f(a0.w - mexp);
            a1.x = exp2f(a1.x - mexp); a1.y = exp2f(a1.y - mexp);
            a1.z = exp2f(a1.z - mexp); a1.w = exp2f(a1.w - mexp);
            a2.x = exp2f(a2.x - mexp); a2.y = exp2f(a2.y - mexp);
            a2.z = exp2f(a2.z - mexp); a2.w = exp2f(a2.w - mexp);
            a3.x = exp2f(a3.x - mexp); a3.y = exp2f(a3.y - mexp);
            a3.z = exp2f(a3.z - mexp); a3.w = exp2f(a3.w - mexp);
            float sm = ((a0.x + a0.y + a0.z + a0.w) + (a1.x + a1.y + a1.z + a1.w))
                     + ((a2.x + a2.y + a2.z + a2.w) + (a3.x + a3.y + a3.z + a3.w));
            sm += __shfl_xor(sm, 1);
            sm += __shfl_xor(sm, 2);
            lreg = al * lreg + sm;
            unsigned w0 = pack2_bf16_rne(a0.x, a0.y);
            unsigned w1 = pack2_bf16_rne(a0.z, a0.w);
            unsigned w2 = pack2_bf16_rne(a1.x, a1.y);
            unsigned w3 = pack2_bf16_rne(a1.z, a1.w);
            unsigned w4 = pack2_bf16_rne(a2.x, a2.y);
            unsigned w5 = pack2_bf16_rne(a2.z, a2.w);
            unsigned w6 = pack2_bf16_rne(a3.x, a3.y);
            unsigned w7 = pack2_bf16_rne(a3.z, a3.w);
            *(uint4*)&sP[row][part * 8]     = make_uint4(w0, w1, w2, w3);
            *(uint4*)&sP[row][part * 8 + 4] = make_uint4(w4, w5, w6, w7);
            if (part == 0) arowS[row] = al;
        }

        __syncthreads();   // B2: sP + arowS published

        // rescale + PV
        #pragma unroll
        for (int ms = 0; ms < 4; ++ms)
            #pragma unroll
            for (int r = 0; r < 4; ++r)
                oacc[ms][r] *= arowS[ms * 16 + quad * 4 + r];

        #pragma unroll
        for (int kt = 0; kt < 2; ++kt) {
            short8 Vf = *(short8*)&vP[c][wave * 16 + lane15][kt * 16 + quad * 4];
            #pragma unroll
            for (int ms = 0; ms < 4; ++ms) {
                short8 Pf = *(short8*)&sP[ms * 16 + lane15][kt * 16 + quad * 4];
                oacc[ms] = __builtin_amdgcn_mfma_f32_16x16x32_bf16(Pf, Vf, oacc[ms], 0, 0, 0);
            }
        }
    }

    // tail column (register state, base-2 domain): 16 dims/thread
    {
        const float* qr = qbuf  + ((size_t)(T0 + row) * NHEAD + h) * 64 + part * 16;
        const float* kr = Ktail + ((size_t)(T0 + row) * NHEAD + h) * 64 + part * 16;
        float dp = 0.f;
        #pragma unroll
        for (int u = 0; u < 4; ++u) {
            float4 qa = *(const float4*)(qr + u * 4);
            float4 ka = *(const float4*)(kr + u * 4);
            dp += qa.x * ka.x + qa.y * ka.y + qa.z * ka.z + qa.w * ka.w;
        }
        dp += __shfl_xor(dp, 1);
        dp += __shfl_xor(dp, 2);
        float tl = dp * SOFTMAX_SCL;
        float mf = fmaxf(mreg, tl);
        float al = exp2f(mreg - mf);
        float pt = exp2f(tl - mf);
        float lf = al * lreg + pt;
        float inv = 1.f / lf;
        if (part == 0) { alS[row] = al * inv; ptS[row] = pt * inv; }
    }
    __syncthreads();

    // final values -> sS (f32) for fragment transpose
    #pragma unroll
    for (int ms = 0; ms < 4; ++ms)
        #pragma unroll
        for (int r = 0; r < 4; ++r) {
            int qrow = ms * 16 + quad * 4 + r;
            int col = wave * 16 + lane15;
            size_t base = ((size_t)(T0 + qrow) * NHEAD + h) * 64 + col;
            sS[qrow][col] = oacc[ms][r] * alS[qrow] + ptS[qrow] * Vtail[base];
        }
    __syncthreads();

    // write single-f16 A-fragments (final GEMM layout): wave = msf, loop kt
    {
        const int msf = wave;
        #pragma unroll
        for (int kt = 0; kt < 2; ++kt) {
            float f[8];
            *(float4*)&f[0] = *(const float4*)&sS[msf * 16 + lane15][kt * 32 + quad * 8];
            *(float4*)&f[4] = *(const float4*)&sS[msf * 16 + lane15][kt * 32 + quad * 8 + 4];
            const size_t frag = (size_t)(b * 4 + msf) * 24 + (2 * h + kt);
            *(half8*)&attf[(frag * 64 + lane) * 8] = cvt8_f16(f);
        }
    }
}

extern "C" void kernel_launch(void* const* d_in, const int* in_sizes, int n_in,
                              void* d_out, int out_size, void* d_ws, size_t ws_size,
                              hipStream_t stream)
{
    const float* x   = (const float*)d_in[0];
    const float* Wq  = (const float*)d_in[1];
    const float* Wk  = (const float*)d_in[2];
    const float* Wv  = (const float*)d_in[3];
    const float* Wks = (const float*)d_in[4];
    const float* bks = (const float*)d_in[5];
    const float* Wvs = (const float*)d_in[6];
    const float* bvs = (const float*)d_in[7];
    const float* Wc  = (const float*)d_in[8];
    const float* bc  = (const float*)d_in[9];
    float* out = (float*)d_out;

    float* ws = (float*)d_ws;
    const size_t TC = (size_t)TLEN * CDIM;
    float* q      = ws;
    float* k      = q + TC;
    float* v      = k + TC;
    float* kkv    = v + TC;
    float* vvv    = kkv + TC;
    float* Kt     = vvv + TC;
    float* Vt     = Kt + TC;
    float* base   = Vt + TC;                      // blobs/scratch region
    _Float16* WblobMap = (_Float16*)base;
    _Float16* blobQKV  = (_Float16*)(base + 262144);
    float* scrK = base + 1146880;
    float* scrV = scrK + 12 * 16 * 64;
    _Float16* blobC = (_Float16*)(base + 1171456);
    unsigned short* KsetH = (unsigned short*)(base + 1466368);
    unsigned short* KsetL = KsetH + 786432;
    unsigned short* VsetB = KsetL + 786432;
    // x f16 fragment blob: alias kkv region; dead before map_f16 writes kkv
    _Float16* xf = (_Float16*)kkv;
    // k as dup-packed u32, v as f16: alias k / v regions
    unsigned*  kdup = (unsigned*)k;
    _Float16*  v16  = (_Float16*)v;
    // attn output fragments: alias vvv region (vvv dead after set_lower)
    _Float16* attf = (_Float16*)vvv;

    prep_all<<<9216 + 2048 + 768, 256, 0, stream>>>(
        Wq, Wk, Wv, Wc, Wks, Wvs, x, blobQKV, blobC, WblobMap, xf);

    gemm_frag<1><<<576, 256, 0, stream>>>(xf, blobQKV, nullptr, q, kdup, v16);

    map_f16<<<(TLEN * NHEAD) / 64, 256, 0, stream>>>(kdup, v16, WblobMap, kkv, vvv);

    set_lower<<<16 * NHEAD, 256, 0, stream>>>(kkv, vvv, bks, bvs, KsetH, KsetL, VsetB, scrK, scrV, Kt, Vt);
    set_upper<<<NHEAD, 256, 0, stream>>>(scrK, scrV, bks, bvs, KsetH, KsetL, VsetB);

    attn_mfma<<<(TLEN / 64) * NHEAD, 256, 0, stream>>>(q, KsetH, KsetL, VsetB, Kt, Vt, attf);

    gemm_frag<0><<<384, 256, 0, stream>>>(attf, blobC, bc, out, nullptr, nullptr);
}

// Round 8
// 192.641 us; speedup vs baseline: 1.0086x; 1.0086x over previous
//
#include <hip/hip_runtime.h>
#include <cstdint>

#define NHEAD 12
#define TLEN 2048
#define CDIM 768
#define NSETS 1023   // 512+256+128+64+32+16+8+4+2+1

typedef __attribute__((ext_vector_type(8))) _Float16 half8;
typedef __attribute__((ext_vector_type(2))) __fp16 fp16x2;
typedef __attribute__((ext_vector_type(8))) short short8;   // 8 bf16
typedef __attribute__((ext_vector_type(8))) unsigned short u16x8;
typedef __attribute__((ext_vector_type(4))) float f32x4;

#define SOFTMAX_SCL 0.18033688011112042f   // 0.125 * log2(e)

__device__ __forceinline__ float elu1(float x) { return x > 0.f ? x + 1.f : __expf(x); }

__device__ __forceinline__ unsigned pack2_bf16_trunc(float a, float b) {
    unsigned ua = __float_as_uint(a), ub = __float_as_uint(b);
    return __builtin_amdgcn_perm(ub, ua, 0x07060302);
}
__device__ __forceinline__ unsigned pack2_bf16_rne(float a, float b) {
    unsigned ua = __float_as_uint(a), ub = __float_as_uint(b);
    ua = ua + 0x7fff + ((ua >> 16) & 1);
    ub = ub + 0x7fff + ((ub >> 16) & 1);
    return (ub & 0xffff0000u) | (ua >> 16);
}
__device__ __forceinline__ unsigned short bf16_hi_trunc(float a) {
    return (unsigned short)(__float_as_uint(a) >> 16);
}
__device__ __forceinline__ unsigned short bf16_lo_trunc(float a) {
    unsigned ua = __float_as_uint(a);
    float r = a - __uint_as_float(ua & 0xffff0000u);
    return (unsigned short)(__float_as_uint(r) >> 16);
}
__device__ __forceinline__ unsigned short bf16_rne(float a) {
    unsigned ua = __float_as_uint(a);
    ua = ua + 0x7fff + ((ua >> 16) & 1);
    return (unsigned short)(ua >> 16);
}
__device__ __forceinline__ short8 mk_short8(const unsigned* u) {
    union { unsigned w[4]; short8 s; } x;
    x.w[0] = u[0]; x.w[1] = u[1]; x.w[2] = u[2]; x.w[3] = u[3];
    return x.s;
}
__device__ __forceinline__ short8 as_s8(u16x8 v) {
    union { u16x8 u; short8 s; } x; x.u = v; return x.s;
}
__device__ __forceinline__ void split8_bf16(const float* f, short8& hi, short8& lo) {
    unsigned hp[4], lp[4];
    #pragma unroll
    for (int p = 0; p < 4; ++p) {
        float a = f[2 * p], b = f[2 * p + 1];
        unsigned ua = __float_as_uint(a), ub = __float_as_uint(b);
        hp[p] = __builtin_amdgcn_perm(ub, ua, 0x07060302);
        float ra = a - __uint_as_float(ua & 0xffff0000u);
        float rb = b - __uint_as_float(ub & 0xffff0000u);
        lp[p] = pack2_bf16_trunc(ra, rb);
    }
    hi = mk_short8(hp); lo = mk_short8(lp);
}
__device__ __forceinline__ half8 cvt8_f16(const float* f) {
    union { fp16x2 h2[4]; half8 h8; } u;
    #pragma unroll
    for (int jp = 0; jp < 4; ++jp)
        u.h2[jp] = __builtin_amdgcn_cvt_pkrtz(f[2 * jp], f[2 * jp + 1]);
    return u.h8;
}

// ---------- merged prep: 4x W768 blobs + map-W blob + x f16 frag blob ----------
__global__ __launch_bounds__(256) void prep_all(
    const float* __restrict__ Wq, const float* __restrict__ Wk,
    const float* __restrict__ Wv, const float* __restrict__ Wc4,
    const float* __restrict__ Wks, const float* __restrict__ Wvs,
    const float* __restrict__ x,
    _Float16* __restrict__ blobQKV, _Float16* __restrict__ blobC,
    _Float16* __restrict__ Wblob,
    _Float16* __restrict__ xf)
{
    const int g = blockIdx.x;
    const int tid = threadIdx.x;
    if (g < 9216) {
        const int sel = g / 2304;
        const float* W = sel == 0 ? Wq : (sel == 1 ? Wk : (sel == 2 ? Wv : Wc4));
        _Float16* blob = (sel < 3) ? (blobQKV + (size_t)sel * 589824) : blobC;
        const int idx = (g % 2304) * 256 + tid;
        const int k = idx / 768, n = idx % 768;
        const int i = k >> 5, kl = k & 31;
        const int quad = kl >> 3, j = kl & 7;
        const int nsg = n >> 4, lane15 = n & 15;
        const int lane = quad * 16 + lane15;
        blob[((size_t)(i * 48 + nsg) * 64 + lane) * 8 + j] = (_Float16)W[idx];
    } else if (g < 9216 + 2048) {
        const int idx = (g - 9216) * 256 + tid;
        const int kk = idx >> 7, n = idx & 127;
        float f = (n < 64) ? Wks[(size_t)kk * 64 + n] : Wvs[(size_t)kk * 64 + (n - 64)];
        const int i = kk >> 6, kl = kk & 63;
        const int ks = kl >> 5, quad = (kl >> 3) & 3, j = kl & 7;
        const int nsg = n >> 4, lane15 = n & 15;
        const int lane = quad * 16 + lane15;
        const size_t off = ((size_t)(((i * 2 + ks) * 8 + nsg)) * 64 + lane) * 8 + j;
        Wblob[off] = (_Float16)f;
    } else {
        // x (2048x768) -> single-f16 fragment-major blob
        const int p = (g - 11264) * 256 + tid;   // one half8 per thread
        const int lane = p & 63, frag = p >> 6;
        const int m16 = frag / 24, k32 = frag - m16 * 24;
        const int row = m16 * 16 + (lane & 15);
        const int col = k32 * 32 + (lane >> 4) * 8;
        float f[8];
        *(float4*)&f[0] = *(const float4*)&x[(size_t)row * CDIM + col];
        *(float4*)&f[4] = *(const float4*)&x[(size_t)row * CDIM + col + 4];
        *(half8*)&xf[(size_t)p * 8] = cvt8_f16(f);
    }
}

// ---------- fragment-direct MFMA GEMM, single-f16 A, BK=64 pipeline ----------
template<int QKV>
__global__ __launch_bounds__(256, 3) void gemm_frag(
    const _Float16* __restrict__ Af,
    const _Float16* __restrict__ Bblobs, const float* __restrict__ bias,
    float* __restrict__ outq, unsigned* __restrict__ kdup,
    _Float16* __restrict__ v16)
{
    const int nbx = QKV ? 18 : 12;
    const int cpx = QKV ? 72 : 48;         // blocks per XCD = nwg/8
    int bid = blockIdx.x;
    bid = (bid & 7) * cpx + (bid >> 3);    // bijective XCD swizzle (nwg % 8 == 0)
    const int by  = bid / nbx;             // row-block (64 rows)
    const int bxg = bid % nbx;
    const int which = QKV ? bxg / 6 : 0;
    const int bxm   = QKV ? bxg % 6 : bxg;
    const half8* __restrict__ Bc = (const half8*)(Bblobs + (size_t)which * 589824);

    const int tid = threadIdx.x;
    const int wave = tid >> 6, lane = tid & 63;
    const int lane15 = lane & 15, quad = lane >> 4;
    const int m16b = by * 4;
    const int nsg0 = QKV ? (bxm * 8 + wave * 2) : (bxm * 4 + wave);

    const half8* __restrict__ Ah = (const half8*)Af;

    f32x4 acc[4][2];
    #pragma unroll
    for (int ms = 0; ms < 4; ++ms) {
        acc[ms][0] = (f32x4){0.f, 0.f, 0.f, 0.f};
        acc[ms][1] = (f32x4){0.f, 0.f, 0.f, 0.f};
    }

    const size_t aBase = ((size_t)m16b * 24) * 64 + lane;   // half8 units
    const size_t bBase = (size_t)nsg0 * 64 + lane;

    half8 aC[2][4], bC[2][2], aN[2][4], bN[2][2];
    auto loadA = [&](half8 (*dst)[4], int k32a) {
        #pragma unroll
        for (int u = 0; u < 2; ++u)
            #pragma unroll
            for (int ms = 0; ms < 4; ++ms)
                dst[u][ms] = Ah[aBase + (size_t)(k32a + u) * 64 + (size_t)ms * (24 * 64)];
    };
    auto loadB = [&](half8 (*dst)[2], int k32a) {
        #pragma unroll
        for (int u = 0; u < 2; ++u) {
            const size_t bo = bBase + (size_t)(k32a + u) * (48 * 64);
            dst[u][0] = Bc[bo];
            if (QKV) dst[u][1] = Bc[bo + 64];
        }
    };

    loadA(aC, 0); loadB(bC, 0);
    for (int kk = 0; kk < 12; ++kk) {
        const bool more = (kk + 1) < 12;
        if (more) { loadA(aN, 2 * kk + 2); loadB(bN, 2 * kk + 2); }
        #pragma unroll
        for (int u = 0; u < 2; ++u)
            #pragma unroll
            for (int ms = 0; ms < 4; ++ms) {
                acc[ms][0] = __builtin_amdgcn_mfma_f32_16x16x32_f16(aC[u][ms], bC[u][0], acc[ms][0], 0, 0, 0);
                if (QKV)
                    acc[ms][1] = __builtin_amdgcn_mfma_f32_16x16x32_f16(aC[u][ms], bC[u][1], acc[ms][1], 0, 0, 0);
            }
        if (more) {
            #pragma unroll
            for (int u = 0; u < 2; ++u) {
                bC[u][0] = bN[u][0]; bC[u][1] = bN[u][1];
                #pragma unroll
                for (int ms = 0; ms < 4; ++ms) aC[u][ms] = aN[u][ms];
            }
        }
    }

    const int NSL = QKV ? 2 : 1;
    #pragma unroll
    for (int ms = 0; ms < 4; ++ms)
        #pragma unroll
        for (int nb = 0; nb < 2; ++nb) {
            if (nb >= NSL) break;
            const int coln = (nsg0 + nb) * 16 + lane15;
            #pragma unroll
            for (int r = 0; r < 4; ++r) {
                const int row = m16b * 16 + ms * 16 + quad * 4 + r;
                float vv = acc[ms][nb][r];
                if (!QKV) {
                    outq[(size_t)row * CDIM + coln] = vv + bias[coln];
                } else if (which == 0) {
                    outq[(size_t)row * CDIM + coln] = elu1(vv);
                } else if (which == 1) {
                    float e = elu1(vv);
                    union { fp16x2 h; unsigned u; } cc;
                    cc.h = __builtin_amdgcn_cvt_pkrtz(e, e);
                    kdup[(size_t)row * CDIM + coln] = cc.u;
                } else {
                    union { fp16x2 h; _Float16 f2[2]; } cc;
                    cc.h = __builtin_amdgcn_cvt_pkrtz(vv, vv);
                    v16[(size_t)row * CDIM + coln] = cc.f2[0];
                }
            }
        }
}

// ---------- MFMA mapped features v8 ----------
__global__ __launch_bounds__(256, 2) void map_f16(
    const unsigned* __restrict__ kdup, const _Float16* __restrict__ v16,
    const _Float16* __restrict__ Wblob,
    float* __restrict__ kkv, float* __restrict__ vvv)
{
    __shared__ unsigned kU[64][65];   // half2(k,k) for 64 positions x 64 dims

    const int tid = threadIdx.x;
    const int p0 = blockIdx.x * 64;
    const int wave = tid >> 6, lane = tid & 63;
    const int lane15 = lane & 15, quad = lane >> 4;

    {
        const int row = tid >> 2, cb = (tid & 3) * 16;
        const unsigned* src = &kdup[(size_t)(p0 + row) * 64 + cb];
        uint4 a0 = *(const uint4*)(src + 0);
        uint4 a1 = *(const uint4*)(src + 4);
        uint4 a2 = *(const uint4*)(src + 8);
        uint4 a3 = *(const uint4*)(src + 12);
        *(uint4*)&kU[row][cb + 0]  = a0;
        *(uint4*)&kU[row][cb + 4]  = a1;
        *(uint4*)&kU[row][cb + 8]  = a2;
        *(uint4*)&kU[row][cb + 12] = a3;
    }

    half8 vrh[4][2];
    #pragma unroll
    for (int mh = 0; mh < 4; ++mh) {
        const size_t pbase = (size_t)(p0 + mh * 16 + lane15) * 64;
        #pragma unroll
        for (int ks = 0; ks < 2; ++ks)
            vrh[mh][ks] = *(const half8*)&v16[pbase + ks * 32 + quad * 8];
    }
    __syncthreads();

    const half8* __restrict__ Wc = (const half8*)Wblob;

    f32x4 acc[4][2];
    #pragma unroll
    for (int mh = 0; mh < 4; ++mh)
        #pragma unroll
        for (int nsl = 0; nsl < 2; ++nsl)
            acc[mh][nsl] = (f32x4){0.f, 0.f, 0.f, 0.f};

    half8 b0[2], b1[2], b2[2], b3[2];
    unsigned ka0[4], ka1[4], ka2[4], ka3[4];

    auto loadB = [&](half8* b, int s) {
        b[0] = Wc[(size_t)(s * 8 + 2 * wave) * 64 + lane];
        b[1] = Wc[(size_t)(s * 8 + 2 * wave + 1) * 64 + lane];
    };
    auto loadK = [&](unsigned* ka, int s) {
        const int i = s >> 1;
        #pragma unroll
        for (int mh = 0; mh < 4; ++mh) ka[mh] = kU[mh * 16 + lane15][i];
    };
    auto compute = [&](const half8* b, const unsigned* ka, int s) {
        const int ks = s & 1;
        #pragma unroll
        for (int mh = 0; mh < 4; ++mh) {
            union { unsigned u; fp16x2 h; } ku; ku.u = ka[mh];
            union { fp16x2 h2[4]; half8 h8; } va, ra;
            va.h8 = vrh[mh][ks];
            #pragma unroll
            for (int jp = 0; jp < 4; ++jp) ra.h2[jp] = ku.h * va.h2[jp];
            acc[mh][0] = __builtin_amdgcn_mfma_f32_16x16x32_f16(ra.h8, b[0], acc[mh][0], 0, 0, 0);
            acc[mh][1] = __builtin_amdgcn_mfma_f32_16x16x32_f16(ra.h8, b[1], acc[mh][1], 0, 0, 0);
        }
    };

    loadB(b0, 0); loadB(b1, 1); loadB(b2, 2); loadB(b3, 3);
    loadK(ka0, 0); loadK(ka1, 1); loadK(ka2, 2); loadK(ka3, 3);
    for (int s = 0; s < 128; s += 4) {
        const bool more = (s + 4) < 128;
        compute(b0, ka0, s);
        compute(b1, ka1, s + 1);
        if (more) { loadB(b0, s + 4); loadK(ka0, s + 4); loadB(b1, s + 5); loadK(ka1, s + 5); }
        compute(b2, ka2, s + 2);
        compute(b3, ka3, s + 3);
        if (more) { loadB(b2, s + 6); loadK(ka2, s + 6); loadB(b3, s + 7); loadK(ka3, s + 7); }
    }

    #pragma unroll
    for (int mh = 0; mh < 4; ++mh)
        #pragma unroll
        for (int nsl = 0; nsl < 2; ++nsl) {
            int n128 = (2 * wave + nsl) * 16 + lane15;
            float* dst = (n128 < 64) ? kkv : vvv;
            int col = n128 & 63;
            #pragma unroll
            for (int r = 0; r < 4; ++r) {
                int p = p0 + mh * 16 + quad * 4 + r;
                dst[(size_t)p * 64 + col] = acc[mh][nsl][r];
            }
        }
}

// ---------- set features: write K pre-split bf16 hi/lo + V bf16 RNE ----------
__global__ __launch_bounds__(256) void set_lower(
    const float* __restrict__ kkv, const float* __restrict__ vvv,
    const float* __restrict__ bks, const float* __restrict__ bvs,
    unsigned short* __restrict__ KsetH, unsigned short* __restrict__ KsetL,
    unsigned short* __restrict__ VsetB,
    float* __restrict__ scrK, float* __restrict__ scrV,
    float* __restrict__ Kt, float* __restrict__ Vt)
{
    __shared__ float curK[63][64];
    __shared__ float curV[63][64];
    const int tid = threadIdx.x;
    const int col = tid & 63, grp = tid >> 6;
    const int h = blockIdx.x % NHEAD;
    const int c = blockIdx.x / NHEAD;
    const int t0 = c * 128;
    const float bk = bks[col], bv = bvs[col];

    for (int j = grp; j < 32; j += 4) {
        const size_t rbase = (size_t)(t0 + j * 4) * CDIM + h * 64 + col;
        const float* pk = kkv + rbase;
        const float* pv = vvv + rbase;
        float* ptK = Kt + rbase;
        float* ptV = Vt + rbase;
        float sk = bk, sv = bv;
        #pragma unroll
        for (int u = 0; u < 4; ++u) {
            sk += pk[(size_t)u * CDIM];
            sv += pv[(size_t)u * CDIM];
            ptK[(size_t)u * CDIM] = sk;
            ptV[(size_t)u * CDIM] = sv;
        }
        curK[j][col] = sk - bk; curV[j][col] = sv - bv;
        size_t o = ((size_t)(c * 32 + j) * NHEAD + h) * 64 + col;
        KsetH[o] = bf16_hi_trunc(sk); KsetL[o] = bf16_lo_trunc(sk);
        VsetB[o] = bf16_rne(sv);
    }
    __syncthreads();

    const int LBASE[6] = {0, 32, 48, 56, 60, 62};
    const int GBASE[6] = {0, 512, 768, 896, 960, 992};
    #pragma unroll
    for (int li = 1; li < 6; ++li) {
        const int ns = 32 >> li;
        for (int j = grp; j < ns; j += 4) {
            float sk = curK[LBASE[li - 1] + 2 * j][col] + curK[LBASE[li - 1] + 2 * j + 1][col];
            float sv = curV[LBASE[li - 1] + 2 * j][col] + curV[LBASE[li - 1] + 2 * j + 1][col];
            curK[LBASE[li] + j][col] = sk; curV[LBASE[li] + j][col] = sv;
            size_t o = ((size_t)(GBASE[li] + c * ns + j) * NHEAD + h) * 64 + col;
            float kv_ = sk + bk, vv_ = sv + bv;
            KsetH[o] = bf16_hi_trunc(kv_); KsetL[o] = bf16_lo_trunc(kv_);
            VsetB[o] = bf16_rne(vv_);
        }
        __syncthreads();
    }

    if (grp == 0) {
        scrK[((size_t)h * 16 + c) * 64 + col] = curK[62][col];
        scrV[((size_t)h * 16 + c) * 64 + col] = curV[62][col];
    }
}

__global__ __launch_bounds__(256) void set_upper(
    const float* __restrict__ scrK, const float* __restrict__ scrV,
    const float* __restrict__ bks, const float* __restrict__ bvs,
    unsigned short* __restrict__ KsetH, unsigned short* __restrict__ KsetL,
    unsigned short* __restrict__ VsetB)
{
    __shared__ float cK[15][64], cV[15][64];
    const int h = blockIdx.x;
    const int tid = threadIdx.x, col = tid & 63, grp = tid >> 6;
    const float bk = bks[col], bv = bvs[col];

    for (int j = grp; j < 8; j += 4) {
        float sk = scrK[((size_t)h * 16 + 2 * j) * 64 + col] + scrK[((size_t)h * 16 + 2 * j + 1) * 64 + col];
        float sv = scrV[((size_t)h * 16 + 2 * j) * 64 + col] + scrV[((size_t)h * 16 + 2 * j + 1) * 64 + col];
        cK[j][col] = sk; cV[j][col] = sv;
        size_t o = ((size_t)(1008 + j) * NHEAD + h) * 64 + col;
        float kv_ = sk + bk, vv_ = sv + bv;
        KsetH[o] = bf16_hi_trunc(kv_); KsetL[o] = bf16_lo_trunc(kv_);
        VsetB[o] = bf16_rne(vv_);
    }
    __syncthreads();
    const int LB[4] = {0, 8, 12, 14};
    const int GB[4] = {1008, 1016, 1020, 1022};
    #pragma unroll
    for (int li = 1; li < 4; ++li) {
        const int ns = 8 >> li;
        for (int j = grp; j < ns; j += 4) {
            float sk = cK[LB[li - 1] + 2 * j][col] + cK[LB[li - 1] + 2 * j + 1][col];
            float sv = cV[LB[li - 1] + 2 * j][col] + cV[LB[li - 1] + 2 * j + 1][col];
            cK[LB[li] + j][col] = sk; cV[LB[li] + j][col] = sv;
            size_t o = ((size_t)(GB[li] + j) * NHEAD + h) * 64 + col;
            float kv_ = sk + bk, vv_ = sv + bv;
            KsetH[o] = bf16_hi_trunc(kv_); KsetL[o] = bf16_lo_trunc(kv_);
            VsetB[o] = bf16_rne(vv_);
        }
        __syncthreads();
    }
}

// ---------- MFMA flash attention v8: 32-row tiles (R6 structure, best measured)
// + single-buffered sS/sP/arowS (barrier chain orders hazards: sS write(t+1) >
// B2(t) > sS reads(t); sP write(t+1) > B1(t+1) > sP reads(t)); only vP (written
// at loop-top vs PV(t-1) reads, no barrier between) stays double-buffered.
// LDS 52.7 -> 37.9 KB => 4 blocks/CU (155 KB < 160 KB), occupancy 12 -> 16
// waves/CU; launch_bounds(256,4) caps VGPR at 128. ----------
__global__ __launch_bounds__(256, 4) void attn_mfma(
    const float* __restrict__ qbuf,
    const unsigned short* __restrict__ KsetH, const unsigned short* __restrict__ KsetL,
    const unsigned short* __restrict__ VsetB,
    const float* __restrict__ Ktail, const float* __restrict__ Vtail,
    _Float16* __restrict__ attf)
{
    __shared__ unsigned ssAll[1024];       // sid | (send<<16)
    __shared__ float sS[32][68];           // masked logits (pre-scaled)
    __shared__ unsigned sP[32][40];        // P as bf16 pairs along k
    __shared__ unsigned vP[2][64][40];     // V^T as bf16 pairs along set
    __shared__ float arowS[32];
    __shared__ float alS[32], ptS[32];

    const int tid = threadIdx.x;
    const int b   = 63 - (blockIdx.x / NHEAD);   // heavy blocks dispatched first
    const int h   = blockIdx.x % NHEAD;
    const int T0  = b * 32;
    const int wave = tid >> 6, lane = tid & 63;
    const int lane15 = lane & 15, quad = lane >> 4;

    const int Tend = T0 + 32;
    const int LOFF[10] = {0, 512, 768, 896, 960, 992, 1008, 1016, 1020, 1022};
    int pfx[10], Vtot = 0;
    #pragma unroll
    for (int li = 0; li < 10; ++li) { pfx[li] = Vtot; Vtot += Tend >> (li + 2); }
    const int ntiles = (Vtot + 63) >> 6;

    for (int j = tid; j < 1024; j += 256) {
        unsigned pk = (4095u << 16);       // send=4095 masks all rows; sid=0 harmless
        if (j < Vtot) {
            int li = 0;
            #pragma unroll
            for (int u = 1; u < 10; ++u) if (j >= pfx[u]) li = u;
            int idx = j - pfx[li];
            pk = (unsigned)(LOFF[li] + idx) | ((unsigned)((idx + 1) << (li + 2)) << 16);
        }
        ssAll[j] = pk;
    }

    short8 Qhi[2][2], Qlo[2][2];
    #pragma unroll
    for (int ms = 0; ms < 2; ++ms)
        #pragma unroll
        for (int kt = 0; kt < 2; ++kt) {
            const float* qp = qbuf + ((size_t)(T0 + ms * 16 + lane15) * NHEAD + h) * 64 + kt * 32 + quad * 8;
            float f[8];
            *(float4*)&f[0] = *(const float4*)qp;
            *(float4*)&f[4] = *(const float4*)(qp + 4);
            split8_bf16(f, Qhi[ms][kt], Qlo[ms][kt]);
        }

    __syncthreads();   // ssAll ready

    const int row = tid >> 3, part = tid & 7;
    float mreg = -1e30f, lreg = 0.f;

    f32x4 oacc[2];
    oacc[0] = (f32x4){0.f, 0.f, 0.f, 0.f};
    oacc[1] = (f32x4){0.f, 0.f, 0.f, 0.f};

    u16x8 Va, Vb;                  // V bf16: 8 dims of even/odd set
    u16x8 KH[2], KL[2];            // K bf16 hi/lo: dims quad*8..+7, +32
    const int sp = tid >> 3, dd = (tid & 7) * 8;
    auto prefV = [&](int tile) {
        int sa = (int)(ssAll[tile * 64 + 2 * sp] & 0xffffu);
        int sb = (int)(ssAll[tile * 64 + 2 * sp + 1] & 0xffffu);
        Va = *(const u16x8*)(VsetB + ((size_t)sa * NHEAD + h) * 64 + dd);
        Vb = *(const u16x8*)(VsetB + ((size_t)sb * NHEAD + h) * 64 + dd);
    };
    auto prefK = [&](int tile) {
        int sK = (int)(ssAll[tile * 64 + wave * 16 + lane15] & 0xffffu);
        const size_t ko = ((size_t)sK * NHEAD + h) * 64 + quad * 8;
        KH[0] = *(const u16x8*)(KsetH + ko);
        KH[1] = *(const u16x8*)(KsetH + ko + 32);
        KL[0] = *(const u16x8*)(KsetL + ko);
        KL[1] = *(const u16x8*)(KsetL + ko + 32);
    };
    prefV(0); prefK(0);

    for (int tile = 0; tile < ntiles; ++tile) {
        const int c = tile & 1;

        // stage V^T bf16 pairs (pure shift-or; other buffer than PV(t-1) reads)
        #pragma unroll
        for (int i = 0; i < 8; ++i)
            vP[c][dd + i][sp] = (unsigned)Va[i] | ((unsigned)Vb[i] << 16);

        // K fragments: direct reinterpret (pre-split)
        short8 Khi[2] = { as_s8(KH[0]), as_s8(KH[1]) };
        short8 Klo[2] = { as_s8(KL[0]), as_s8(KL[1]) };

        // QK^T 3-term split
        f32x4 lacc[2];
        lacc[0] = (f32x4){0.f, 0.f, 0.f, 0.f};
        lacc[1] = (f32x4){0.f, 0.f, 0.f, 0.f};
        #pragma unroll
        for (int kt = 0; kt < 2; ++kt)
            #pragma unroll
            for (int ms = 0; ms < 2; ++ms) {
                lacc[ms] = __builtin_amdgcn_mfma_f32_16x16x32_bf16(Qhi[ms][kt], Khi[kt], lacc[ms], 0, 0, 0);
                lacc[ms] = __builtin_amdgcn_mfma_f32_16x16x32_bf16(Qlo[ms][kt], Khi[kt], lacc[ms], 0, 0, 0);
                lacc[ms] = __builtin_amdgcn_mfma_f32_16x16x32_bf16(Qhi[ms][kt], Klo[kt], lacc[ms], 0, 0, 0);
            }

        // mask + scale (base-2 domain) -> sS (write ordered after prior
        // softmax reads by B2 of previous iteration)
        {
            const int sendv = (int)(ssAll[tile * 64 + wave * 16 + lane15] >> 16);
            #pragma unroll
            for (int ms = 0; ms < 2; ++ms)
                #pragma unroll
                for (int r = 0; r < 4; ++r) {
                    int qrow = ms * 16 + quad * 4 + r;
                    bool ok = (T0 + qrow + 1) >= sendv;
                    sS[qrow][wave * 16 + lane15] = ok ? lacc[ms][r] * SOFTMAX_SCL : -1e30f;
                }
        }

        // issue prefetch for next tile
        if (tile + 1 < ntiles) { prefV(tile + 1); prefK(tile + 1); }

        __syncthreads();   // B1: sS + vP[c] published; prior-tile PV complete

        // register softmax (base-2, guard-free)
        {
            float4 a = *(float4*)&sS[row][part * 8];
            float4 c4 = *(float4*)&sS[row][part * 8 + 4];
            float mx = fmaxf(fmaxf(fmaxf(a.x, a.y), fmaxf(a.z, a.w)),
                             fmaxf(fmaxf(c4.x, c4.y), fmaxf(c4.z, c4.w)));
            mx = fmaxf(mx, __shfl_xor(mx, 1));
            mx = fmaxf(mx, __shfl_xor(mx, 2));
            mx = fmaxf(mx, __shfl_xor(mx, 4));
            float mnew = fmaxf(mreg, mx);
            float al = exp2f(mreg - mnew);
            mreg = mnew;
            float mexp = fmaxf(mnew, -1e28f);
            a.x = exp2f(a.x - mexp);
            a.y = exp2f(a.y - mexp);
            a.z = exp2f(a.z - mexp);
            a.w = exp2f(a.w - mexp);
            c4.x = exp2f(c4.x - mexp);
            c4.y = exp2f(c4.y - mexp);
            c4.z = exp2f(c4.z - mexp);
            c4.w = exp2f(c4.w - mexp);
            float sm = (a.x + a.y + a.z + a.w) + (c4.x + c4.y + c4.z + c4.w);
            sm += __shfl_xor(sm, 1);
            sm += __shfl_xor(sm, 2);
            sm += __shfl_xor(sm, 4);
            lreg = al * lreg + sm;
            unsigned w0 = pack2_bf16_rne(a.x, a.y);
            unsigned w1 = pack2_bf16_rne(a.z, a.w);
            unsigned w2 = pack2_bf16_rne(c4.x, c4.y);
            unsigned w3 = pack2_bf16_rne(c4.z, c4.w);
            *(uint4*)&sP[row][part * 4] = make_uint4(w0, w1, w2, w3);
            if (part == 0) arowS[row] = al;
        }

        __syncthreads();   // B2: sP + arowS published

        // rescale + PV
        #pragma unroll
        for (int ms = 0; ms < 2; ++ms)
            #pragma unroll
            for (int r = 0; r < 4; ++r)
                oacc[ms][r] *= arowS[ms * 16 + quad * 4 + r];

        #pragma unroll
        for (int kt = 0; kt < 2; ++kt) {
            short8 Vf = *(short8*)&vP[c][wave * 16 + lane15][kt * 16 + quad * 4];
            #pragma unroll
            for (int ms = 0; ms < 2; ++ms) {
                short8 Pf = *(short8*)&sP[ms * 16 + lane15][kt * 16 + quad * 4];
                oacc[ms] = __builtin_amdgcn_mfma_f32_16x16x32_bf16(Pf, Vf, oacc[ms], 0, 0, 0);
            }
        }
    }

    // tail column (register state, base-2 domain)
    {
        const float* qr = qbuf  + ((size_t)(T0 + row) * NHEAD + h) * 64 + part * 8;
        const float* kr = Ktail + ((size_t)(T0 + row) * NHEAD + h) * 64 + part * 8;
        float4 qa = *(const float4*)qr, qb = *(const float4*)(qr + 4);
        float4 ka = *(const float4*)kr, kb = *(const float4*)(kr + 4);
        float dp = qa.x * ka.x + qa.y * ka.y + qa.z * ka.z + qa.w * ka.w
                 + qb.x * kb.x + qb.y * kb.y + qb.z * kb.z + qb.w * kb.w;
        dp += __shfl_xor(dp, 1);
        dp += __shfl_xor(dp, 2);
        dp += __shfl_xor(dp, 4);
        float tl = dp * SOFTMAX_SCL;
        float mf = fmaxf(mreg, tl);
        float al = exp2f(mreg - mf);
        float pt = exp2f(tl - mf);
        float lf = al * lreg + pt;
        float inv = 1.f / lf;
        if (part == 0) { alS[row] = al * inv; ptS[row] = pt * inv; }
    }
    __syncthreads();

    // final values -> sS (f32) for fragment transpose
    #pragma unroll
    for (int ms = 0; ms < 2; ++ms)
        #pragma unroll
        for (int r = 0; r < 4; ++r) {
            int qrow = ms * 16 + quad * 4 + r;
            int col = wave * 16 + lane15;
            size_t base = ((size_t)(T0 + qrow) * NHEAD + h) * 64 + col;
            sS[qrow][col] = oacc[ms][r] * alS[qrow] + ptS[qrow] * Vtail[base];
        }
    __syncthreads();

    // write single-f16 A-fragments (final GEMM layout) directly
    {
        const int kt = wave >> 1, msf = wave & 1;
        float f[8];
        *(float4*)&f[0] = *(const float4*)&sS[msf * 16 + lane15][kt * 32 + quad * 8];
        *(float4*)&f[4] = *(const float4*)&sS[msf * 16 + lane15][kt * 32 + quad * 8 + 4];
        const size_t frag = (size_t)(b * 2 + msf) * 24 + (2 * h + kt);
        *(half8*)&attf[(frag * 64 + lane) * 8] = cvt8_f16(f);
    }
}

extern "C" void kernel_launch(void* const* d_in, const int* in_sizes, int n_in,
                              void* d_out, int out_size, void* d_ws, size_t ws_size,
                              hipStream_t stream)
{
    const float* x   = (const float*)d_in[0];
    const float* Wq  = (const float*)d_in[1];
    const float* Wk  = (const float*)d_in[2];
    const float* Wv  = (const float*)d_in[3];
    const float* Wks = (const float*)d_in[4];
    const float* bks = (const float*)d_in[5];
    const float* Wvs = (const float*)d_in[6];
    const float* bvs = (const float*)d_in[7];
    const float* Wc  = (const float*)d_in[8];
    const float* bc  = (const float*)d_in[9];
    float* out = (float*)d_out;

    float* ws = (float*)d_ws;
    const size_t TC = (size_t)TLEN * CDIM;
    float* q      = ws;
    float* k      = q + TC;
    float* v      = k + TC;
    float* kkv    = v + TC;
    float* vvv    = kkv + TC;
    float* Kt     = vvv + TC;
    float* Vt     = Kt + TC;
    float* base   = Vt + TC;                      // blobs/scratch region
    _Float16* WblobMap = (_Float16*)base;
    _Float16* blobQKV  = (_Float16*)(base + 262144);
    float* scrK = base + 1146880;
    float* scrV = scrK + 12 * 16 * 64;
    _Float16* blobC = (_Float16*)(base + 1171456);
    unsigned short* KsetH = (unsigned short*)(base + 1466368);
    unsigned short* KsetL = KsetH + 786432;
    unsigned short* VsetB = KsetL + 786432;
    // x f16 fragment blob: alias kkv region; dead before map_f16 writes kkv
    _Float16* xf = (_Float16*)kkv;
    // k as dup-packed u32, v as f16: alias k / v regions
    unsigned*  kdup = (unsigned*)k;
    _Float16*  v16  = (_Float16*)v;
    // attn output fragments: alias vvv region (vvv dead after set_lower)
    _Float16* attf = (_Float16*)vvv;

    prep_all<<<9216 + 2048 + 768, 256, 0, stream>>>(
        Wq, Wk, Wv, Wc, Wks, Wvs, x, blobQKV, blobC, WblobMap, xf);

    gemm_frag<1><<<576, 256, 0, stream>>>(xf, blobQKV, nullptr, q, kdup, v16);

    map_f16<<<(TLEN * NHEAD) / 64, 256, 0, stream>>>(kdup, v16, WblobMap, kkv, vvv);

    set_lower<<<16 * NHEAD, 256, 0, stream>>>(kkv, vvv, bks, bvs, KsetH, KsetL, VsetB, scrK, scrV, Kt, Vt);
    set_upper<<<NHEAD, 256, 0, stream>>>(scrK, scrV, bks, bvs, KsetH, KsetL, VsetB);

    attn_mfma<<<(TLEN / 32) * NHEAD, 256, 0, stream>>>(q, KsetH, KsetL, VsetB, Kt, Vt, attf);

    gemm_frag<0><<<384, 256, 0, stream>>>(attf, blobC, bc, out, nullptr, nullptr);
}

// Round 9
// 191.073 us; speedup vs baseline: 1.0169x; 1.0082x over previous
//
#include <hip/hip_runtime.h>
#include <cstdint>

#define NHEAD 12
#define TLEN 2048
#define CDIM 768
#define NSETS 1023   // 512+256+128+64+32+16+8+4+2+1

typedef __attribute__((ext_vector_type(8))) _Float16 half8;
typedef __attribute__((ext_vector_type(2))) __fp16 fp16x2;
typedef __attribute__((ext_vector_type(8))) short short8;   // 8 bf16
typedef __attribute__((ext_vector_type(8))) unsigned short u16x8;
typedef __attribute__((ext_vector_type(4))) float f32x4;

#define SOFTMAX_SCL 0.18033688011112042f   // 0.125 * log2(e)

__device__ __forceinline__ float elu1(float x) { return x > 0.f ? x + 1.f : __expf(x); }

__device__ __forceinline__ unsigned pack2_bf16_trunc(float a, float b) {
    unsigned ua = __float_as_uint(a), ub = __float_as_uint(b);
    return __builtin_amdgcn_perm(ub, ua, 0x07060302);
}
__device__ __forceinline__ unsigned pack2_bf16_rne(float a, float b) {
    unsigned ua = __float_as_uint(a), ub = __float_as_uint(b);
    ua = ua + 0x7fff + ((ua >> 16) & 1);
    ub = ub + 0x7fff + ((ub >> 16) & 1);
    return (ub & 0xffff0000u) | (ua >> 16);
}
__device__ __forceinline__ unsigned short bf16_hi_trunc(float a) {
    return (unsigned short)(__float_as_uint(a) >> 16);
}
__device__ __forceinline__ unsigned short bf16_lo_trunc(float a) {
    unsigned ua = __float_as_uint(a);
    float r = a - __uint_as_float(ua & 0xffff0000u);
    return (unsigned short)(__float_as_uint(r) >> 16);
}
__device__ __forceinline__ unsigned short bf16_rne(float a) {
    unsigned ua = __float_as_uint(a);
    ua = ua + 0x7fff + ((ua >> 16) & 1);
    return (unsigned short)(ua >> 16);
}
__device__ __forceinline__ short8 mk_short8(const unsigned* u) {
    union { unsigned w[4]; short8 s; } x;
    x.w[0] = u[0]; x.w[1] = u[1]; x.w[2] = u[2]; x.w[3] = u[3];
    return x.s;
}
__device__ __forceinline__ short8 as_s8(u16x8 v) {
    union { u16x8 u; short8 s; } x; x.u = v; return x.s;
}
__device__ __forceinline__ void split8_bf16(const float* f, short8& hi, short8& lo) {
    unsigned hp[4], lp[4];
    #pragma unroll
    for (int p = 0; p < 4; ++p) {
        float a = f[2 * p], b = f[2 * p + 1];
        unsigned ua = __float_as_uint(a), ub = __float_as_uint(b);
        hp[p] = __builtin_amdgcn_perm(ub, ua, 0x07060302);
        float ra = a - __uint_as_float(ua & 0xffff0000u);
        float rb = b - __uint_as_float(ub & 0xffff0000u);
        lp[p] = pack2_bf16_trunc(ra, rb);
    }
    hi = mk_short8(hp); lo = mk_short8(lp);
}
__device__ __forceinline__ half8 cvt8_f16(const float* f) {
    union { fp16x2 h2[4]; half8 h8; } u;
    #pragma unroll
    for (int jp = 0; jp < 4; ++jp)
        u.h2[jp] = __builtin_amdgcn_cvt_pkrtz(f[2 * jp], f[2 * jp + 1]);
    return u.h8;
}

// ---------- merged prep: 4x W768 blobs + map-W blob + x f16 frag blob ----------
__global__ __launch_bounds__(256) void prep_all(
    const float* __restrict__ Wq, const float* __restrict__ Wk,
    const float* __restrict__ Wv, const float* __restrict__ Wc4,
    const float* __restrict__ Wks, const float* __restrict__ Wvs,
    const float* __restrict__ x,
    _Float16* __restrict__ blobQKV, _Float16* __restrict__ blobC,
    _Float16* __restrict__ Wblob,
    _Float16* __restrict__ xf)
{
    const int g = blockIdx.x;
    const int tid = threadIdx.x;
    if (g < 9216) {
        const int sel = g / 2304;
        const float* W = sel == 0 ? Wq : (sel == 1 ? Wk : (sel == 2 ? Wv : Wc4));
        _Float16* blob = (sel < 3) ? (blobQKV + (size_t)sel * 589824) : blobC;
        const int idx = (g % 2304) * 256 + tid;
        const int k = idx / 768, n = idx % 768;
        const int i = k >> 5, kl = k & 31;
        const int quad = kl >> 3, j = kl & 7;
        const int nsg = n >> 4, lane15 = n & 15;
        const int lane = quad * 16 + lane15;
        blob[((size_t)(i * 48 + nsg) * 64 + lane) * 8 + j] = (_Float16)W[idx];
    } else if (g < 9216 + 2048) {
        const int idx = (g - 9216) * 256 + tid;
        const int kk = idx >> 7, n = idx & 127;
        float f = (n < 64) ? Wks[(size_t)kk * 64 + n] : Wvs[(size_t)kk * 64 + (n - 64)];
        const int i = kk >> 6, kl = kk & 63;
        const int ks = kl >> 5, quad = (kl >> 3) & 3, j = kl & 7;
        const int nsg = n >> 4, lane15 = n & 15;
        const int lane = quad * 16 + lane15;
        const size_t off = ((size_t)(((i * 2 + ks) * 8 + nsg)) * 64 + lane) * 8 + j;
        Wblob[off] = (_Float16)f;
    } else {
        // x (2048x768) -> single-f16 fragment-major blob
        const int p = (g - 11264) * 256 + tid;   // one half8 per thread
        const int lane = p & 63, frag = p >> 6;
        const int m16 = frag / 24, k32 = frag - m16 * 24;
        const int row = m16 * 16 + (lane & 15);
        const int col = k32 * 32 + (lane >> 4) * 8;
        float f[8];
        *(float4*)&f[0] = *(const float4*)&x[(size_t)row * CDIM + col];
        *(float4*)&f[4] = *(const float4*)&x[(size_t)row * CDIM + col + 4];
        *(half8*)&xf[(size_t)p * 8] = cvt8_f16(f);
    }
}

// ---------- fragment-direct MFMA GEMM, single-f16 A, BK=64 pipeline ----------
template<int QKV>
__global__ __launch_bounds__(256, 3) void gemm_frag(
    const _Float16* __restrict__ Af,
    const _Float16* __restrict__ Bblobs, const float* __restrict__ bias,
    float* __restrict__ outq, unsigned* __restrict__ kdup,
    _Float16* __restrict__ v16)
{
    const int nbx = QKV ? 18 : 12;
    const int cpx = QKV ? 72 : 48;         // blocks per XCD = nwg/8
    int bid = blockIdx.x;
    bid = (bid & 7) * cpx + (bid >> 3);    // bijective XCD swizzle (nwg % 8 == 0)
    const int by  = bid / nbx;             // row-block (64 rows)
    const int bxg = bid % nbx;
    const int which = QKV ? bxg / 6 : 0;
    const int bxm   = QKV ? bxg % 6 : bxg;
    const half8* __restrict__ Bc = (const half8*)(Bblobs + (size_t)which * 589824);

    const int tid = threadIdx.x;
    const int wave = tid >> 6, lane = tid & 63;
    const int lane15 = lane & 15, quad = lane >> 4;
    const int m16b = by * 4;
    const int nsg0 = QKV ? (bxm * 8 + wave * 2) : (bxm * 4 + wave);

    const half8* __restrict__ Ah = (const half8*)Af;

    f32x4 acc[4][2];
    #pragma unroll
    for (int ms = 0; ms < 4; ++ms) {
        acc[ms][0] = (f32x4){0.f, 0.f, 0.f, 0.f};
        acc[ms][1] = (f32x4){0.f, 0.f, 0.f, 0.f};
    }

    const size_t aBase = ((size_t)m16b * 24) * 64 + lane;   // half8 units
    const size_t bBase = (size_t)nsg0 * 64 + lane;

    half8 aC[2][4], bC[2][2], aN[2][4], bN[2][2];
    auto loadA = [&](half8 (*dst)[4], int k32a) {
        #pragma unroll
        for (int u = 0; u < 2; ++u)
            #pragma unroll
            for (int ms = 0; ms < 4; ++ms)
                dst[u][ms] = Ah[aBase + (size_t)(k32a + u) * 64 + (size_t)ms * (24 * 64)];
    };
    auto loadB = [&](half8 (*dst)[2], int k32a) {
        #pragma unroll
        for (int u = 0; u < 2; ++u) {
            const size_t bo = bBase + (size_t)(k32a + u) * (48 * 64);
            dst[u][0] = Bc[bo];
            if (QKV) dst[u][1] = Bc[bo + 64];
        }
    };

    loadA(aC, 0); loadB(bC, 0);
    for (int kk = 0; kk < 12; ++kk) {
        const bool more = (kk + 1) < 12;
        if (more) { loadA(aN, 2 * kk + 2); loadB(bN, 2 * kk + 2); }
        #pragma unroll
        for (int u = 0; u < 2; ++u)
            #pragma unroll
            for (int ms = 0; ms < 4; ++ms) {
                acc[ms][0] = __builtin_amdgcn_mfma_f32_16x16x32_f16(aC[u][ms], bC[u][0], acc[ms][0], 0, 0, 0);
                if (QKV)
                    acc[ms][1] = __builtin_amdgcn_mfma_f32_16x16x32_f16(aC[u][ms], bC[u][1], acc[ms][1], 0, 0, 0);
            }
        if (more) {
            #pragma unroll
            for (int u = 0; u < 2; ++u) {
                bC[u][0] = bN[u][0]; bC[u][1] = bN[u][1];
                #pragma unroll
                for (int ms = 0; ms < 4; ++ms) aC[u][ms] = aN[u][ms];
            }
        }
    }

    const int NSL = QKV ? 2 : 1;
    #pragma unroll
    for (int ms = 0; ms < 4; ++ms)
        #pragma unroll
        for (int nb = 0; nb < 2; ++nb) {
            if (nb >= NSL) break;
            const int coln = (nsg0 + nb) * 16 + lane15;
            #pragma unroll
            for (int r = 0; r < 4; ++r) {
                const int row = m16b * 16 + ms * 16 + quad * 4 + r;
                float vv = acc[ms][nb][r];
                if (!QKV) {
                    outq[(size_t)row * CDIM + coln] = vv + bias[coln];
                } else if (which == 0) {
                    outq[(size_t)row * CDIM + coln] = elu1(vv);
                } else if (which == 1) {
                    float e = elu1(vv);
                    union { fp16x2 h; unsigned u; } cc;
                    cc.h = __builtin_amdgcn_cvt_pkrtz(e, e);
                    kdup[(size_t)row * CDIM + coln] = cc.u;
                } else {
                    union { fp16x2 h; _Float16 f2[2]; } cc;
                    cc.h = __builtin_amdgcn_cvt_pkrtz(vv, vv);
                    v16[(size_t)row * CDIM + coln] = cc.f2[0];
                }
            }
        }
}

// ---------- MFMA mapped features v8 ----------
__global__ __launch_bounds__(256, 2) void map_f16(
    const unsigned* __restrict__ kdup, const _Float16* __restrict__ v16,
    const _Float16* __restrict__ Wblob,
    float* __restrict__ kkv, float* __restrict__ vvv)
{
    __shared__ unsigned kU[64][65];   // half2(k,k) for 64 positions x 64 dims

    const int tid = threadIdx.x;
    const int p0 = blockIdx.x * 64;
    const int wave = tid >> 6, lane = tid & 63;
    const int lane15 = lane & 15, quad = lane >> 4;

    {
        const int row = tid >> 2, cb = (tid & 3) * 16;
        const unsigned* src = &kdup[(size_t)(p0 + row) * 64 + cb];
        uint4 a0 = *(const uint4*)(src + 0);
        uint4 a1 = *(const uint4*)(src + 4);
        uint4 a2 = *(const uint4*)(src + 8);
        uint4 a3 = *(const uint4*)(src + 12);
        *(uint4*)&kU[row][cb + 0]  = a0;
        *(uint4*)&kU[row][cb + 4]  = a1;
        *(uint4*)&kU[row][cb + 8]  = a2;
        *(uint4*)&kU[row][cb + 12] = a3;
    }

    half8 vrh[4][2];
    #pragma unroll
    for (int mh = 0; mh < 4; ++mh) {
        const size_t pbase = (size_t)(p0 + mh * 16 + lane15) * 64;
        #pragma unroll
        for (int ks = 0; ks < 2; ++ks)
            vrh[mh][ks] = *(const half8*)&v16[pbase + ks * 32 + quad * 8];
    }
    __syncthreads();

    const half8* __restrict__ Wc = (const half8*)Wblob;

    f32x4 acc[4][2];
    #pragma unroll
    for (int mh = 0; mh < 4; ++mh)
        #pragma unroll
        for (int nsl = 0; nsl < 2; ++nsl)
            acc[mh][nsl] = (f32x4){0.f, 0.f, 0.f, 0.f};

    half8 b0[2], b1[2], b2[2], b3[2];
    unsigned ka0[4], ka1[4], ka2[4], ka3[4];

    auto loadB = [&](half8* b, int s) {
        b[0] = Wc[(size_t)(s * 8 + 2 * wave) * 64 + lane];
        b[1] = Wc[(size_t)(s * 8 + 2 * wave + 1) * 64 + lane];
    };
    auto loadK = [&](unsigned* ka, int s) {
        const int i = s >> 1;
        #pragma unroll
        for (int mh = 0; mh < 4; ++mh) ka[mh] = kU[mh * 16 + lane15][i];
    };
    auto compute = [&](const half8* b, const unsigned* ka, int s) {
        const int ks = s & 1;
        #pragma unroll
        for (int mh = 0; mh < 4; ++mh) {
            union { unsigned u; fp16x2 h; } ku; ku.u = ka[mh];
            union { fp16x2 h2[4]; half8 h8; } va, ra;
            va.h8 = vrh[mh][ks];
            #pragma unroll
            for (int jp = 0; jp < 4; ++jp) ra.h2[jp] = ku.h * va.h2[jp];
            acc[mh][0] = __builtin_amdgcn_mfma_f32_16x16x32_f16(ra.h8, b[0], acc[mh][0], 0, 0, 0);
            acc[mh][1] = __builtin_amdgcn_mfma_f32_16x16x32_f16(ra.h8, b[1], acc[mh][1], 0, 0, 0);
        }
    };

    loadB(b0, 0); loadB(b1, 1); loadB(b2, 2); loadB(b3, 3);
    loadK(ka0, 0); loadK(ka1, 1); loadK(ka2, 2); loadK(ka3, 3);
    for (int s = 0; s < 128; s += 4) {
        const bool more = (s + 4) < 128;
        compute(b0, ka0, s);
        compute(b1, ka1, s + 1);
        if (more) { loadB(b0, s + 4); loadK(ka0, s + 4); loadB(b1, s + 5); loadK(ka1, s + 5); }
        compute(b2, ka2, s + 2);
        compute(b3, ka3, s + 3);
        if (more) { loadB(b2, s + 6); loadK(ka2, s + 6); loadB(b3, s + 7); loadK(ka3, s + 7); }
    }

    #pragma unroll
    for (int mh = 0; mh < 4; ++mh)
        #pragma unroll
        for (int nsl = 0; nsl < 2; ++nsl) {
            int n128 = (2 * wave + nsl) * 16 + lane15;
            float* dst = (n128 < 64) ? kkv : vvv;
            int col = n128 & 63;
            #pragma unroll
            for (int r = 0; r < 4; ++r) {
                int p = p0 + mh * 16 + quad * 4 + r;
                dst[(size_t)p * 64 + col] = acc[mh][nsl][r];
            }
        }
}

// ---------- set features: K pre-split bf16 hi/lo + V bf16 RNE; tail V bf16 ----------
__global__ __launch_bounds__(256) void set_lower(
    const float* __restrict__ kkv, const float* __restrict__ vvv,
    const float* __restrict__ bks, const float* __restrict__ bvs,
    unsigned short* __restrict__ KsetH, unsigned short* __restrict__ KsetL,
    unsigned short* __restrict__ VsetB,
    float* __restrict__ scrK, float* __restrict__ scrV,
    float* __restrict__ Kt, unsigned short* __restrict__ Vtb)
{
    __shared__ float curK[63][64];
    __shared__ float curV[63][64];
    const int tid = threadIdx.x;
    const int col = tid & 63, grp = tid >> 6;
    const int h = blockIdx.x % NHEAD;
    const int c = blockIdx.x / NHEAD;
    const int t0 = c * 128;
    const float bk = bks[col], bv = bvs[col];

    for (int j = grp; j < 32; j += 4) {
        const size_t rbase = (size_t)(t0 + j * 4) * CDIM + h * 64 + col;
        const float* pk = kkv + rbase;
        const float* pv = vvv + rbase;
        float* ptK = Kt + rbase;
        unsigned short* ptV = Vtb + rbase;
        float sk = bk, sv = bv;
        #pragma unroll
        for (int u = 0; u < 4; ++u) {
            sk += pk[(size_t)u * CDIM];
            sv += pv[(size_t)u * CDIM];
            ptK[(size_t)u * CDIM] = sk;
            ptV[(size_t)u * CDIM] = bf16_rne(sv);
        }
        curK[j][col] = sk - bk; curV[j][col] = sv - bv;
        size_t o = ((size_t)(c * 32 + j) * NHEAD + h) * 64 + col;
        KsetH[o] = bf16_hi_trunc(sk); KsetL[o] = bf16_lo_trunc(sk);
        VsetB[o] = bf16_rne(sv);
    }
    __syncthreads();

    const int LBASE[6] = {0, 32, 48, 56, 60, 62};
    const int GBASE[6] = {0, 512, 768, 896, 960, 992};
    #pragma unroll
    for (int li = 1; li < 6; ++li) {
        const int ns = 32 >> li;
        for (int j = grp; j < ns; j += 4) {
            float sk = curK[LBASE[li - 1] + 2 * j][col] + curK[LBASE[li - 1] + 2 * j + 1][col];
            float sv = curV[LBASE[li - 1] + 2 * j][col] + curV[LBASE[li - 1] + 2 * j + 1][col];
            curK[LBASE[li] + j][col] = sk; curV[LBASE[li] + j][col] = sv;
            size_t o = ((size_t)(GBASE[li] + c * ns + j) * NHEAD + h) * 64 + col;
            float kv_ = sk + bk, vv_ = sv + bv;
            KsetH[o] = bf16_hi_trunc(kv_); KsetL[o] = bf16_lo_trunc(kv_);
            VsetB[o] = bf16_rne(vv_);
        }
        __syncthreads();
    }

    if (grp == 0) {
        scrK[((size_t)h * 16 + c) * 64 + col] = curK[62][col];
        scrV[((size_t)h * 16 + c) * 64 + col] = curV[62][col];
    }
}

__global__ __launch_bounds__(256) void set_upper(
    const float* __restrict__ scrK, const float* __restrict__ scrV,
    const float* __restrict__ bks, const float* __restrict__ bvs,
    unsigned short* __restrict__ KsetH, unsigned short* __restrict__ KsetL,
    unsigned short* __restrict__ VsetB)
{
    __shared__ float cK[15][64], cV[15][64];
    const int h = blockIdx.x;
    const int tid = threadIdx.x, col = tid & 63, grp = tid >> 6;
    const float bk = bks[col], bv = bvs[col];

    for (int j = grp; j < 8; j += 4) {
        float sk = scrK[((size_t)h * 16 + 2 * j) * 64 + col] + scrK[((size_t)h * 16 + 2 * j + 1) * 64 + col];
        float sv = scrV[((size_t)h * 16 + 2 * j) * 64 + col] + scrV[((size_t)h * 16 + 2 * j + 1) * 64 + col];
        cK[j][col] = sk; cV[j][col] = sv;
        size_t o = ((size_t)(1008 + j) * NHEAD + h) * 64 + col;
        float kv_ = sk + bk, vv_ = sv + bv;
        KsetH[o] = bf16_hi_trunc(kv_); KsetL[o] = bf16_lo_trunc(kv_);
        VsetB[o] = bf16_rne(vv_);
    }
    __syncthreads();
    const int LB[4] = {0, 8, 12, 14};
    const int GB[4] = {1008, 1016, 1020, 1022};
    #pragma unroll
    for (int li = 1; li < 4; ++li) {
        const int ns = 8 >> li;
        for (int j = grp; j < ns; j += 4) {
            float sk = cK[LB[li - 1] + 2 * j][col] + cK[LB[li - 1] + 2 * j + 1][col];
            float sv = cV[LB[li - 1] + 2 * j][col] + cV[LB[li - 1] + 2 * j + 1][col];
            cK[LB[li] + j][col] = sk; cV[LB[li] + j][col] = sv;
            size_t o = ((size_t)(GB[li] + j) * NHEAD + h) * 64 + col;
            float kv_ = sk + bk, vv_ = sv + bv;
            KsetH[o] = bf16_hi_trunc(kv_); KsetL[o] = bf16_lo_trunc(kv_);
            VsetB[o] = bf16_rne(vv_);
        }
        __syncthreads();
    }
}

// ---------- MFMA flash attention v9: 32-row tiles, single-buffered sS/sP,
// mask fast-path (__any gate: most wave-tiles fully visible), earlier K/V
// prefetch issue (extra QK-MFMA latency cover), bf16 tail-V ----------
__global__ __launch_bounds__(256, 3) void attn_mfma(
    const float* __restrict__ qbuf,
    const unsigned short* __restrict__ KsetH, const unsigned short* __restrict__ KsetL,
    const unsigned short* __restrict__ VsetB,
    const float* __restrict__ Ktail, const unsigned short* __restrict__ Vtb,
    _Float16* __restrict__ attf)
{
    __shared__ unsigned ssAll[1024];       // sid | (send<<16)
    __shared__ float sS[32][68];           // masked logits (pre-scaled)
    __shared__ unsigned sP[32][40];        // P as bf16 pairs along k
    __shared__ unsigned vP[2][64][40];     // V^T as bf16 pairs along set
    __shared__ float arowS[32];
    __shared__ float alS[32], ptS[32];

    const int tid = threadIdx.x;
    const int b   = 63 - (blockIdx.x / NHEAD);   // heavy blocks dispatched first
    const int h   = blockIdx.x % NHEAD;
    const int T0  = b * 32;
    const int wave = tid >> 6, lane = tid & 63;
    const int lane15 = lane & 15, quad = lane >> 4;

    const int Tend = T0 + 32;
    const int LOFF[10] = {0, 512, 768, 896, 960, 992, 1008, 1016, 1020, 1022};
    int pfx[10], Vtot = 0;
    #pragma unroll
    for (int li = 0; li < 10; ++li) { pfx[li] = Vtot; Vtot += Tend >> (li + 2); }
    const int ntiles = (Vtot + 63) >> 6;

    for (int j = tid; j < 1024; j += 256) {
        unsigned pk = (4095u << 16);       // send=4095 masks all rows; sid=0 harmless
        if (j < Vtot) {
            int li = 0;
            #pragma unroll
            for (int u = 1; u < 10; ++u) if (j >= pfx[u]) li = u;
            int idx = j - pfx[li];
            pk = (unsigned)(LOFF[li] + idx) | ((unsigned)((idx + 1) << (li + 2)) << 16);
        }
        ssAll[j] = pk;
    }

    short8 Qhi[2][2], Qlo[2][2];
    #pragma unroll
    for (int ms = 0; ms < 2; ++ms)
        #pragma unroll
        for (int kt = 0; kt < 2; ++kt) {
            const float* qp = qbuf + ((size_t)(T0 + ms * 16 + lane15) * NHEAD + h) * 64 + kt * 32 + quad * 8;
            float f[8];
            *(float4*)&f[0] = *(const float4*)qp;
            *(float4*)&f[4] = *(const float4*)(qp + 4);
            split8_bf16(f, Qhi[ms][kt], Qlo[ms][kt]);
        }

    __syncthreads();   // ssAll ready

    const int row = tid >> 3, part = tid & 7;
    float mreg = -1e30f, lreg = 0.f;

    f32x4 oacc[2];
    oacc[0] = (f32x4){0.f, 0.f, 0.f, 0.f};
    oacc[1] = (f32x4){0.f, 0.f, 0.f, 0.f};

    u16x8 Va, Vb;                  // V bf16: 8 dims of even/odd set
    u16x8 KH[2], KL[2];            // K bf16 hi/lo: dims quad*8..+7, +32
    const int sp = tid >> 3, dd = (tid & 7) * 8;
    auto prefV = [&](int tile) {
        int sa = (int)(ssAll[tile * 64 + 2 * sp] & 0xffffu);
        int sb = (int)(ssAll[tile * 64 + 2 * sp + 1] & 0xffffu);
        Va = *(const u16x8*)(VsetB + ((size_t)sa * NHEAD + h) * 64 + dd);
        Vb = *(const u16x8*)(VsetB + ((size_t)sb * NHEAD + h) * 64 + dd);
    };
    auto prefK = [&](int tile) {
        int sK = (int)(ssAll[tile * 64 + wave * 16 + lane15] & 0xffffu);
        const size_t ko = ((size_t)sK * NHEAD + h) * 64 + quad * 8;
        KH[0] = *(const u16x8*)(KsetH + ko);
        KH[1] = *(const u16x8*)(KsetH + ko + 32);
        KL[0] = *(const u16x8*)(KsetL + ko);
        KL[1] = *(const u16x8*)(KsetL + ko + 32);
    };
    prefV(0); prefK(0);

    for (int tile = 0; tile < ntiles; ++tile) {
        const int c = tile & 1;

        // stage V^T bf16 pairs (pure shift-or; other buffer than PV(t-1) reads)
        #pragma unroll
        for (int i = 0; i < 8; ++i)
            vP[c][dd + i][sp] = (unsigned)Va[i] | ((unsigned)Vb[i] << 16);

        // K fragments: direct reinterpret (pre-split)
        short8 Khi[2] = { as_s8(KH[0]), as_s8(KH[1]) };
        short8 Klo[2] = { as_s8(KL[0]), as_s8(KL[1]) };

        // grab this tile's send before prefetch overwrites nothing (ssAll const)
        const int sendv = (int)(ssAll[tile * 64 + wave * 16 + lane15] >> 16);

        // issue prefetch for next tile EARLY: Va/Vb/KH/KL are dead now, and
        // the loads gain the QK-MFMA + mask window of latency cover
        if (tile + 1 < ntiles) { prefV(tile + 1); prefK(tile + 1); }

        // QK^T 3-term split
        f32x4 lacc[2];
        lacc[0] = (f32x4){0.f, 0.f, 0.f, 0.f};
        lacc[1] = (f32x4){0.f, 0.f, 0.f, 0.f};
        #pragma unroll
        for (int kt = 0; kt < 2; ++kt)
            #pragma unroll
            for (int ms = 0; ms < 2; ++ms) {
                lacc[ms] = __builtin_amdgcn_mfma_f32_16x16x32_bf16(Qhi[ms][kt], Khi[kt], lacc[ms], 0, 0, 0);
                lacc[ms] = __builtin_amdgcn_mfma_f32_16x16x32_bf16(Qlo[ms][kt], Khi[kt], lacc[ms], 0, 0, 0);
                lacc[ms] = __builtin_amdgcn_mfma_f32_16x16x32_bf16(Qhi[ms][kt], Klo[kt], lacc[ms], 0, 0, 0);
            }

        // mask + scale (base-2 domain) -> sS.  Fast path: if NO column in this
        // wave needs masking (send <= T0+1 => visible to every row), skip the
        // per-element cmp+sel chain entirely (wave-uniform branch).
        if (!__any(sendv > T0 + 1)) {
            #pragma unroll
            for (int ms = 0; ms < 2; ++ms)
                #pragma unroll
                for (int r = 0; r < 4; ++r) {
                    int qrow = ms * 16 + quad * 4 + r;
                    sS[qrow][wave * 16 + lane15] = lacc[ms][r] * SOFTMAX_SCL;
                }
        } else {
            #pragma unroll
            for (int ms = 0; ms < 2; ++ms)
                #pragma unroll
                for (int r = 0; r < 4; ++r) {
                    int qrow = ms * 16 + quad * 4 + r;
                    bool ok = (T0 + qrow + 1) >= sendv;
                    sS[qrow][wave * 16 + lane15] = ok ? lacc[ms][r] * SOFTMAX_SCL : -1e30f;
                }
        }

        __syncthreads();   // B1: sS + vP[c] published; prior-tile PV complete

        // register softmax (base-2, guard-free)
        {
            float4 a = *(float4*)&sS[row][part * 8];
            float4 c4 = *(float4*)&sS[row][part * 8 + 4];
            float mx = fmaxf(fmaxf(fmaxf(a.x, a.y), fmaxf(a.z, a.w)),
                             fmaxf(fmaxf(c4.x, c4.y), fmaxf(c4.z, c4.w)));
            mx = fmaxf(mx, __shfl_xor(mx, 1));
            mx = fmaxf(mx, __shfl_xor(mx, 2));
            mx = fmaxf(mx, __shfl_xor(mx, 4));
            float mnew = fmaxf(mreg, mx);
            float al = exp2f(mreg - mnew);
            mreg = mnew;
            float mexp = fmaxf(mnew, -1e28f);
            a.x = exp2f(a.x - mexp);
            a.y = exp2f(a.y - mexp);
            a.z = exp2f(a.z - mexp);
            a.w = exp2f(a.w - mexp);
            c4.x = exp2f(c4.x - mexp);
            c4.y = exp2f(c4.y - mexp);
            c4.z = exp2f(c4.z - mexp);
            c4.w = exp2f(c4.w - mexp);
            float sm = (a.x + a.y + a.z + a.w) + (c4.x + c4.y + c4.z + c4.w);
            sm += __shfl_xor(sm, 1);
            sm += __shfl_xor(sm, 2);
            sm += __shfl_xor(sm, 4);
            lreg = al * lreg + sm;
            unsigned w0 = pack2_bf16_rne(a.x, a.y);
            unsigned w1 = pack2_bf16_rne(a.z, a.w);
            unsigned w2 = pack2_bf16_rne(c4.x, c4.y);
            unsigned w3 = pack2_bf16_rne(c4.z, c4.w);
            *(uint4*)&sP[row][part * 4] = make_uint4(w0, w1, w2, w3);
            if (part == 0) arowS[row] = al;
        }

        __syncthreads();   // B2: sP + arowS published

        // rescale + PV
        #pragma unroll
        for (int ms = 0; ms < 2; ++ms)
            #pragma unroll
            for (int r = 0; r < 4; ++r)
                oacc[ms][r] *= arowS[ms * 16 + quad * 4 + r];

        #pragma unroll
        for (int kt = 0; kt < 2; ++kt) {
            short8 Vf = *(short8*)&vP[c][wave * 16 + lane15][kt * 16 + quad * 4];
            #pragma unroll
            for (int ms = 0; ms < 2; ++ms) {
                short8 Pf = *(short8*)&sP[ms * 16 + lane15][kt * 16 + quad * 4];
                oacc[ms] = __builtin_amdgcn_mfma_f32_16x16x32_bf16(Pf, Vf, oacc[ms], 0, 0, 0);
            }
        }
    }

    // tail column (register state, base-2 domain)
    {
        const float* qr = qbuf  + ((size_t)(T0 + row) * NHEAD + h) * 64 + part * 8;
        const float* kr = Ktail + ((size_t)(T0 + row) * NHEAD + h) * 64 + part * 8;
        float4 qa = *(const float4*)qr, qb = *(const float4*)(qr + 4);
        float4 ka = *(const float4*)kr, kb = *(const float4*)(kr + 4);
        float dp = qa.x * ka.x + qa.y * ka.y + qa.z * ka.z + qa.w * ka.w
                 + qb.x * kb.x + qb.y * kb.y + qb.z * kb.z + qb.w * kb.w;
        dp += __shfl_xor(dp, 1);
        dp += __shfl_xor(dp, 2);
        dp += __shfl_xor(dp, 4);
        float tl = dp * SOFTMAX_SCL;
        float mf = fmaxf(mreg, tl);
        float al = exp2f(mreg - mf);
        float pt = exp2f(tl - mf);
        float lf = al * lreg + pt;
        float inv = 1.f / lf;
        if (part == 0) { alS[row] = al * inv; ptS[row] = pt * inv; }
    }
    __syncthreads();

    // final values -> sS (f32) for fragment transpose; tail V is bf16
    #pragma unroll
    for (int ms = 0; ms < 2; ++ms)
        #pragma unroll
        for (int r = 0; r < 4; ++r) {
            int qrow = ms * 16 + quad * 4 + r;
            int col = wave * 16 + lane15;
            size_t base = ((size_t)(T0 + qrow) * NHEAD + h) * 64 + col;
            float vt = __uint_as_float((unsigned)Vtb[base] << 16);
            sS[qrow][col] = oacc[ms][r] * alS[qrow] + ptS[qrow] * vt;
        }
    __syncthreads();

    // write single-f16 A-fragments (final GEMM layout) directly
    {
        const int kt = wave >> 1, msf = wave & 1;
        float f[8];
        *(float4*)&f[0] = *(const float4*)&sS[msf * 16 + lane15][kt * 32 + quad * 8];
        *(float4*)&f[4] = *(const float4*)&sS[msf * 16 + lane15][kt * 32 + quad * 8 + 4];
        const size_t frag = (size_t)(b * 2 + msf) * 24 + (2 * h + kt);
        *(half8*)&attf[(frag * 64 + lane) * 8] = cvt8_f16(f);
    }
}

extern "C" void kernel_launch(void* const* d_in, const int* in_sizes, int n_in,
                              void* d_out, int out_size, void* d_ws, size_t ws_size,
                              hipStream_t stream)
{
    const float* x   = (const float*)d_in[0];
    const float* Wq  = (const float*)d_in[1];
    const float* Wk  = (const float*)d_in[2];
    const float* Wv  = (const float*)d_in[3];
    const float* Wks = (const float*)d_in[4];
    const float* bks = (const float*)d_in[5];
    const float* Wvs = (const float*)d_in[6];
    const float* bvs = (const float*)d_in[7];
    const float* Wc  = (const float*)d_in[8];
    const float* bc  = (const float*)d_in[9];
    float* out = (float*)d_out;

    float* ws = (float*)d_ws;
    const size_t TC = (size_t)TLEN * CDIM;
    float* q      = ws;
    float* k      = q + TC;
    float* v      = k + TC;
    float* kkv    = v + TC;
    float* vvv    = kkv + TC;
    float* Kt     = vvv + TC;
    float* Vt     = Kt + TC;
    float* base   = Vt + TC;                      // blobs/scratch region
    _Float16* WblobMap = (_Float16*)base;
    _Float16* blobQKV  = (_Float16*)(base + 262144);
    float* scrK = base + 1146880;
    float* scrV = scrK + 12 * 16 * 64;
    _Float16* blobC = (_Float16*)(base + 1171456);
    unsigned short* KsetH = (unsigned short*)(base + 1466368);
    unsigned short* KsetL = KsetH + 786432;
    unsigned short* VsetB = KsetL + 786432;
    // x f16 fragment blob: alias kkv region; dead before map_f16 writes kkv
    _Float16* xf = (_Float16*)kkv;
    // k as dup-packed u32, v as f16: alias k / v regions
    unsigned*  kdup = (unsigned*)k;
    _Float16*  v16  = (_Float16*)v;
    // tail V as bf16: alias Vt region (half the bytes)
    unsigned short* Vtb = (unsigned short*)Vt;
    // attn output fragments: alias vvv region (vvv dead after set_lower)
    _Float16* attf = (_Float16*)vvv;

    prep_all<<<9216 + 2048 + 768, 256, 0, stream>>>(
        Wq, Wk, Wv, Wc, Wks, Wvs, x, blobQKV, blobC, WblobMap, xf);

    gemm_frag<1><<<576, 256, 0, stream>>>(xf, blobQKV, nullptr, q, kdup, v16);

    map_f16<<<(TLEN * NHEAD) / 64, 256, 0, stream>>>(kdup, v16, WblobMap, kkv, vvv);

    set_lower<<<16 * NHEAD, 256, 0, stream>>>(kkv, vvv, bks, bvs, KsetH, KsetL, VsetB, scrK, scrV, Kt, Vtb);
    set_upper<<<NHEAD, 256, 0, stream>>>(scrK, scrV, bks, bvs, KsetH, KsetL, VsetB);

    attn_mfma<<<(TLEN / 32) * NHEAD, 256, 0, stream>>>(q, KsetH, KsetL, VsetB, Kt, Vtb, attf);

    gemm_frag<0><<<384, 256, 0, stream>>>(attf, blobC, bc, out, nullptr, nullptr);
}

// Round 11
// 181.949 us; speedup vs baseline: 1.0679x; 1.0501x over previous
//
#include <hip/hip_runtime.h>
#include <cstdint>

#define NHEAD 12
#define TLEN 2048
#define CDIM 768
#define NSETS 1023   // 512+256+128+64+32+16+8+4+2+1

typedef __attribute__((ext_vector_type(8))) _Float16 half8;
typedef __attribute__((ext_vector_type(2))) __fp16 fp16x2;
typedef __attribute__((ext_vector_type(8))) short short8;   // 8 bf16
typedef __attribute__((ext_vector_type(8))) unsigned short u16x8;
typedef __attribute__((ext_vector_type(4))) float f32x4;

#define SOFTMAX_SCL 0.18033688011112042f   // 0.125 * log2(e)

__device__ __forceinline__ float elu1(float x) { return x > 0.f ? x + 1.f : __expf(x); }

__device__ __forceinline__ unsigned pack2_bf16_trunc(float a, float b) {
    unsigned ua = __float_as_uint(a), ub = __float_as_uint(b);
    return __builtin_amdgcn_perm(ub, ua, 0x07060302);
}
__device__ __forceinline__ unsigned pack2_bf16_rne(float a, float b) {
    unsigned ua = __float_as_uint(a), ub = __float_as_uint(b);
    ua = ua + 0x7fff + ((ua >> 16) & 1);
    ub = ub + 0x7fff + ((ub >> 16) & 1);
    return (ub & 0xffff0000u) | (ua >> 16);
}
__device__ __forceinline__ unsigned short bf16_hi_trunc(float a) {
    return (unsigned short)(__float_as_uint(a) >> 16);
}
__device__ __forceinline__ unsigned short bf16_lo_trunc(float a) {
    unsigned ua = __float_as_uint(a);
    float r = a - __uint_as_float(ua & 0xffff0000u);
    return (unsigned short)(__float_as_uint(r) >> 16);
}
__device__ __forceinline__ unsigned short bf16_rne(float a) {
    unsigned ua = __float_as_uint(a);
    ua = ua + 0x7fff + ((ua >> 16) & 1);
    return (unsigned short)(ua >> 16);
}
__device__ __forceinline__ short8 mk_short8(const unsigned* u) {
    union { unsigned w[4]; short8 s; } x;
    x.w[0] = u[0]; x.w[1] = u[1]; x.w[2] = u[2]; x.w[3] = u[3];
    return x.s;
}
__device__ __forceinline__ short8 as_s8(u16x8 v) {
    union { u16x8 u; short8 s; } x; x.u = v; return x.s;
}
__device__ __forceinline__ void split8_bf16(const float* f, short8& hi, short8& lo) {
    unsigned hp[4], lp[4];
    #pragma unroll
    for (int p = 0; p < 4; ++p) {
        float a = f[2 * p], b = f[2 * p + 1];
        unsigned ua = __float_as_uint(a), ub = __float_as_uint(b);
        hp[p] = __builtin_amdgcn_perm(ub, ua, 0x07060302);
        float ra = a - __uint_as_float(ua & 0xffff0000u);
        float rb = b - __uint_as_float(ub & 0xffff0000u);
        lp[p] = pack2_bf16_trunc(ra, rb);
    }
    hi = mk_short8(hp); lo = mk_short8(lp);
}
__device__ __forceinline__ half8 cvt8_f16(const float* f) {
    union { fp16x2 h2[4]; half8 h8; } u;
    #pragma unroll
    for (int jp = 0; jp < 4; ++jp)
        u.h2[jp] = __builtin_amdgcn_cvt_pkrtz(f[2 * jp], f[2 * jp + 1]);
    return u.h8;
}

// ---------- merged prep v2: coalesced half8 blob writes (each thread owns the
// 8 contiguous j-slots of one fragment; kills the 8x write amplification of
// per-element 2B scattered stores), 2176 blocks total ----------
__global__ __launch_bounds__(256) void prep_all(
    const float* __restrict__ Wq, const float* __restrict__ Wk,
    const float* __restrict__ Wv, const float* __restrict__ Wc4,
    const float* __restrict__ Wks, const float* __restrict__ Wvs,
    const float* __restrict__ x,
    _Float16* __restrict__ blobQKV, _Float16* __restrict__ blobC,
    _Float16* __restrict__ Wblob,
    _Float16* __restrict__ xf)
{
    const int g = blockIdx.x;
    const int tid = threadIdx.x;
    if (g < 1152) {
        // four 768x768 W -> f16 fragment-major blobs; one half8 per thread
        const int T = g * 256 + tid;             // [0, 4*73728)
        const int sel = T / 73728;
        const int q = T - sel * 73728;           // (i*48 + nsg)*64 + lane
        const float* W = sel == 0 ? Wq : (sel == 1 ? Wk : (sel == 2 ? Wv : Wc4));
        _Float16* blob = (sel < 3) ? (blobQKV + (size_t)sel * 589824) : blobC;
        const int lane = q & 63;
        const int inl = q >> 6;
        const int nsg = inl % 48, i = inl / 48;
        const int quad = lane >> 4, lane15 = lane & 15;
        const int n = nsg * 16 + lane15;
        const int kb = i * 32 + quad * 8;
        half8 hv;
        #pragma unroll
        for (int j = 0; j < 8; ++j)
            hv[j] = (_Float16)W[(size_t)(kb + j) * 768 + n];
        *(half8*)&blob[(size_t)q * 8] = hv;
    } else if (g < 1152 + 256) {
        // map W (4096x128) -> f16 fragment-major blob; one half8 per thread
        const int q = (g - 1152) * 256 + tid;    // ((i*2+ks)*8+nsg)*64 + lane
        const int lane = q & 63;
        const int r1 = q >> 6;
        const int nsg = r1 & 7;
        const int r2 = r1 >> 3;
        const int ks = r2 & 1, i = r2 >> 1;
        const int quad = lane >> 4, lane15 = lane & 15;
        const int n = nsg * 16 + lane15;
        const int kkb = i * 64 + ks * 32 + quad * 8;
        half8 hv;
        #pragma unroll
        for (int j = 0; j < 8; ++j) {
            float f = (n < 64) ? Wks[(size_t)(kkb + j) * 64 + n]
                               : Wvs[(size_t)(kkb + j) * 64 + (n - 64)];
            hv[j] = (_Float16)f;
        }
        *(half8*)&Wblob[(size_t)q * 8] = hv;
    } else {
        // x (2048x768) -> single-f16 fragment-major blob
        const int p = (g - 1408) * 256 + tid;    // one half8 per thread
        const int lane = p & 63, frag = p >> 6;
        const int m16 = frag / 24, k32 = frag - m16 * 24;
        const int row = m16 * 16 + (lane & 15);
        const int col = k32 * 32 + (lane >> 4) * 8;
        float f[8];
        *(float4*)&f[0] = *(const float4*)&x[(size_t)row * CDIM + col];
        *(float4*)&f[4] = *(const float4*)&x[(size_t)row * CDIM + col + 4];
        *(half8*)&xf[(size_t)p * 8] = cvt8_f16(f);
    }
}

// ---------- fragment-direct MFMA GEMM, single-f16 A, BK=64 pipeline ----------
template<int QKV>
__global__ __launch_bounds__(256, 3) void gemm_frag(
    const _Float16* __restrict__ Af,
    const _Float16* __restrict__ Bblobs, const float* __restrict__ bias,
    float* __restrict__ outq, unsigned* __restrict__ kdup,
    _Float16* __restrict__ v16)
{
    const int nbx = QKV ? 18 : 12;
    const int cpx = QKV ? 72 : 48;         // blocks per XCD = nwg/8
    int bid = blockIdx.x;
    bid = (bid & 7) * cpx + (bid >> 3);    // bijective XCD swizzle (nwg % 8 == 0)
    const int by  = bid / nbx;             // row-block (64 rows)
    const int bxg = bid % nbx;
    const int which = QKV ? bxg / 6 : 0;
    const int bxm   = QKV ? bxg % 6 : bxg;
    const half8* __restrict__ Bc = (const half8*)(Bblobs + (size_t)which * 589824);

    const int tid = threadIdx.x;
    const int wave = tid >> 6, lane = tid & 63;
    const int lane15 = lane & 15, quad = lane >> 4;
    const int m16b = by * 4;
    const int nsg0 = QKV ? (bxm * 8 + wave * 2) : (bxm * 4 + wave);

    const half8* __restrict__ Ah = (const half8*)Af;

    f32x4 acc[4][2];
    #pragma unroll
    for (int ms = 0; ms < 4; ++ms) {
        acc[ms][0] = (f32x4){0.f, 0.f, 0.f, 0.f};
        acc[ms][1] = (f32x4){0.f, 0.f, 0.f, 0.f};
    }

    const size_t aBase = ((size_t)m16b * 24) * 64 + lane;   // half8 units
    const size_t bBase = (size_t)nsg0 * 64 + lane;

    half8 aC[2][4], bC[2][2], aN[2][4], bN[2][2];
    auto loadA = [&](half8 (*dst)[4], int k32a) {
        #pragma unroll
        for (int u = 0; u < 2; ++u)
            #pragma unroll
            for (int ms = 0; ms < 4; ++ms)
                dst[u][ms] = Ah[aBase + (size_t)(k32a + u) * 64 + (size_t)ms * (24 * 64)];
    };
    auto loadB = [&](half8 (*dst)[2], int k32a) {
        #pragma unroll
        for (int u = 0; u < 2; ++u) {
            const size_t bo = bBase + (size_t)(k32a + u) * (48 * 64);
            dst[u][0] = Bc[bo];
            if (QKV) dst[u][1] = Bc[bo + 64];
        }
    };

    loadA(aC, 0); loadB(bC, 0);
    for (int kk = 0; kk < 12; ++kk) {
        const bool more = (kk + 1) < 12;
        if (more) { loadA(aN, 2 * kk + 2); loadB(bN, 2 * kk + 2); }
        #pragma unroll
        for (int u = 0; u < 2; ++u)
            #pragma unroll
            for (int ms = 0; ms < 4; ++ms) {
                acc[ms][0] = __builtin_amdgcn_mfma_f32_16x16x32_f16(aC[u][ms], bC[u][0], acc[ms][0], 0, 0, 0);
                if (QKV)
                    acc[ms][1] = __builtin_amdgcn_mfma_f32_16x16x32_f16(aC[u][ms], bC[u][1], acc[ms][1], 0, 0, 0);
            }
        if (more) {
            #pragma unroll
            for (int u = 0; u < 2; ++u) {
                bC[u][0] = bN[u][0]; bC[u][1] = bN[u][1];
                #pragma unroll
                for (int ms = 0; ms < 4; ++ms) aC[u][ms] = aN[u][ms];
            }
        }
    }

    const int NSL = QKV ? 2 : 1;
    #pragma unroll
    for (int ms = 0; ms < 4; ++ms)
        #pragma unroll
        for (int nb = 0; nb < 2; ++nb) {
            if (nb >= NSL) break;
            const int coln = (nsg0 + nb) * 16 + lane15;
            #pragma unroll
            for (int r = 0; r < 4; ++r) {
                const int row = m16b * 16 + ms * 16 + quad * 4 + r;
                float vv = acc[ms][nb][r];
                if (!QKV) {
                    outq[(size_t)row * CDIM + coln] = vv + bias[coln];
                } else if (which == 0) {
                    outq[(size_t)row * CDIM + coln] = elu1(vv);
                } else if (which == 1) {
                    float e = elu1(vv);
                    union { fp16x2 h; unsigned u; } cc;
                    cc.h = __builtin_amdgcn_cvt_pkrtz(e, e);
                    kdup[(size_t)row * CDIM + coln] = cc.u;
                } else {
                    union { fp16x2 h; _Float16 f2[2]; } cc;
                    cc.h = __builtin_amdgcn_cvt_pkrtz(vv, vv);
                    v16[(size_t)row * CDIM + coln] = cc.f2[0];
                }
            }
        }
}

// ---------- MFMA mapped features v9: f16 outputs (halves kkv/vvv traffic;
// rounding 5e-4 << existing f16-input path error) ----------
__global__ __launch_bounds__(256, 2) void map_f16(
    const unsigned* __restrict__ kdup, const _Float16* __restrict__ v16,
    const _Float16* __restrict__ Wblob,
    _Float16* __restrict__ kkv, _Float16* __restrict__ vvv)
{
    __shared__ unsigned kU[64][65];   // half2(k,k) for 64 positions x 64 dims

    const int tid = threadIdx.x;
    const int p0 = blockIdx.x * 64;
    const int wave = tid >> 6, lane = tid & 63;
    const int lane15 = lane & 15, quad = lane >> 4;

    {
        const int row = tid >> 2, cb = (tid & 3) * 16;
        const unsigned* src = &kdup[(size_t)(p0 + row) * 64 + cb];
        uint4 a0 = *(const uint4*)(src + 0);
        uint4 a1 = *(const uint4*)(src + 4);
        uint4 a2 = *(const uint4*)(src + 8);
        uint4 a3 = *(const uint4*)(src + 12);
        *(uint4*)&kU[row][cb + 0]  = a0;
        *(uint4*)&kU[row][cb + 4]  = a1;
        *(uint4*)&kU[row][cb + 8]  = a2;
        *(uint4*)&kU[row][cb + 12] = a3;
    }

    half8 vrh[4][2];
    #pragma unroll
    for (int mh = 0; mh < 4; ++mh) {
        const size_t pbase = (size_t)(p0 + mh * 16 + lane15) * 64;
        #pragma unroll
        for (int ks = 0; ks < 2; ++ks)
            vrh[mh][ks] = *(const half8*)&v16[pbase + ks * 32 + quad * 8];
    }
    __syncthreads();

    const half8* __restrict__ Wc = (const half8*)Wblob;

    f32x4 acc[4][2];
    #pragma unroll
    for (int mh = 0; mh < 4; ++mh)
        #pragma unroll
        for (int nsl = 0; nsl < 2; ++nsl)
            acc[mh][nsl] = (f32x4){0.f, 0.f, 0.f, 0.f};

    half8 b0[2], b1[2], b2[2], b3[2];
    unsigned ka0[4], ka1[4], ka2[4], ka3[4];

    auto loadB = [&](half8* b, int s) {
        b[0] = Wc[(size_t)(s * 8 + 2 * wave) * 64 + lane];
        b[1] = Wc[(size_t)(s * 8 + 2 * wave + 1) * 64 + lane];
    };
    auto loadK = [&](unsigned* ka, int s) {
        const int i = s >> 1;
        #pragma unroll
        for (int mh = 0; mh < 4; ++mh) ka[mh] = kU[mh * 16 + lane15][i];
    };
    auto compute = [&](const half8* b, const unsigned* ka, int s) {
        const int ks = s & 1;
        #pragma unroll
        for (int mh = 0; mh < 4; ++mh) {
            union { unsigned u; fp16x2 h; } ku; ku.u = ka[mh];
            union { fp16x2 h2[4]; half8 h8; } va, ra;
            va.h8 = vrh[mh][ks];
            #pragma unroll
            for (int jp = 0; jp < 4; ++jp) ra.h2[jp] = ku.h * va.h2[jp];
            acc[mh][0] = __builtin_amdgcn_mfma_f32_16x16x32_f16(ra.h8, b[0], acc[mh][0], 0, 0, 0);
            acc[mh][1] = __builtin_amdgcn_mfma_f32_16x16x32_f16(ra.h8, b[1], acc[mh][1], 0, 0, 0);
        }
    };

    loadB(b0, 0); loadB(b1, 1); loadB(b2, 2); loadB(b3, 3);
    loadK(ka0, 0); loadK(ka1, 1); loadK(ka2, 2); loadK(ka3, 3);
    for (int s = 0; s < 128; s += 4) {
        const bool more = (s + 4) < 128;
        compute(b0, ka0, s);
        compute(b1, ka1, s + 1);
        if (more) { loadB(b0, s + 4); loadK(ka0, s + 4); loadB(b1, s + 5); loadK(ka1, s + 5); }
        compute(b2, ka2, s + 2);
        compute(b3, ka3, s + 3);
        if (more) { loadB(b2, s + 6); loadK(ka2, s + 6); loadB(b3, s + 7); loadK(ka3, s + 7); }
    }

    #pragma unroll
    for (int mh = 0; mh < 4; ++mh)
        #pragma unroll
        for (int nsl = 0; nsl < 2; ++nsl) {
            int n128 = (2 * wave + nsl) * 16 + lane15;
            _Float16* dst = (n128 < 64) ? kkv : vvv;
            int col = n128 & 63;
            #pragma unroll
            for (int r = 0; r < 4; ++r) {
                int p = p0 + mh * 16 + quad * 4 + r;
                dst[(size_t)p * 64 + col] = (_Float16)acc[mh][nsl][r];
            }
        }
}

// ---------- set features: K pre-split bf16 hi/lo + V bf16 RNE; tail V bf16;
// f16 kkv/vvv inputs (f32 accumulation) ----------
__global__ __launch_bounds__(256) void set_lower(
    const _Float16* __restrict__ kkv, const _Float16* __restrict__ vvv,
    const float* __restrict__ bks, const float* __restrict__ bvs,
    unsigned short* __restrict__ KsetH, unsigned short* __restrict__ KsetL,
    unsigned short* __restrict__ VsetB,
    float* __restrict__ scrK, float* __restrict__ scrV,
    float* __restrict__ Kt, unsigned short* __restrict__ Vtb)
{
    __shared__ float curK[63][64];
    __shared__ float curV[63][64];
    const int tid = threadIdx.x;
    const int col = tid & 63, grp = tid >> 6;
    const int h = blockIdx.x % NHEAD;
    const int c = blockIdx.x / NHEAD;
    const int t0 = c * 128;
    const float bk = bks[col], bv = bvs[col];

    for (int j = grp; j < 32; j += 4) {
        const size_t rbase = (size_t)(t0 + j * 4) * CDIM + h * 64 + col;
        const _Float16* pk = kkv + rbase;
        const _Float16* pv = vvv + rbase;
        float* ptK = Kt + rbase;
        unsigned short* ptV = Vtb + rbase;
        float sk = bk, sv = bv;
        #pragma unroll
        for (int u = 0; u < 4; ++u) {
            sk += (float)pk[(size_t)u * CDIM];
            sv += (float)pv[(size_t)u * CDIM];
            ptK[(size_t)u * CDIM] = sk;
            ptV[(size_t)u * CDIM] = bf16_rne(sv);
        }
        curK[j][col] = sk - bk; curV[j][col] = sv - bv;
        size_t o = ((size_t)(c * 32 + j) * NHEAD + h) * 64 + col;
        KsetH[o] = bf16_hi_trunc(sk); KsetL[o] = bf16_lo_trunc(sk);
        VsetB[o] = bf16_rne(sv);
    }
    __syncthreads();

    const int LBASE[6] = {0, 32, 48, 56, 60, 62};
    const int GBASE[6] = {0, 512, 768, 896, 960, 992};
    #pragma unroll
    for (int li = 1; li < 6; ++li) {
        const int ns = 32 >> li;
        for (int j = grp; j < ns; j += 4) {
            float sk = curK[LBASE[li - 1] + 2 * j][col] + curK[LBASE[li - 1] + 2 * j + 1][col];
            float sv = curV[LBASE[li - 1] + 2 * j][col] + curV[LBASE[li - 1] + 2 * j + 1][col];
            curK[LBASE[li] + j][col] = sk; curV[LBASE[li] + j][col] = sv;
            size_t o = ((size_t)(GBASE[li] + c * ns + j) * NHEAD + h) * 64 + col;
            float kv_ = sk + bk, vv_ = sv + bv;
            KsetH[o] = bf16_hi_trunc(kv_); KsetL[o] = bf16_lo_trunc(kv_);
            VsetB[o] = bf16_rne(vv_);
        }
        __syncthreads();
    }

    if (grp == 0) {
        scrK[((size_t)h * 16 + c) * 64 + col] = curK[62][col];
        scrV[((size_t)h * 16 + c) * 64 + col] = curV[62][col];
    }
}

__global__ __launch_bounds__(256) void set_upper(
    const float* __restrict__ scrK, const float* __restrict__ scrV,
    const float* __restrict__ bks, const float* __restrict__ bvs,
    unsigned short* __restrict__ KsetH, unsigned short* __restrict__ KsetL,
    unsigned short* __restrict__ VsetB)
{
    __shared__ float cK[15][64], cV[15][64];
    const int h = blockIdx.x;
    const int tid = threadIdx.x, col = tid & 63, grp = tid >> 6;
    const float bk = bks[col], bv = bvs[col];

    for (int j = grp; j < 8; j += 4) {
        float sk = scrK[((size_t)h * 16 + 2 * j) * 64 + col] + scrK[((size_t)h * 16 + 2 * j + 1) * 64 + col];
        float sv = scrV[((size_t)h * 16 + 2 * j) * 64 + col] + scrV[((size_t)h * 16 + 2 * j + 1) * 64 + col];
        cK[j][col] = sk; cV[j][col] = sv;
        size_t o = ((size_t)(1008 + j) * NHEAD + h) * 64 + col;
        float kv_ = sk + bk, vv_ = sv + bv;
        KsetH[o] = bf16_hi_trunc(kv_); KsetL[o] = bf16_lo_trunc(kv_);
        VsetB[o] = bf16_rne(vv_);
    }
    __syncthreads();
    const int LB[4] = {0, 8, 12, 14};
    const int GB[4] = {1008, 1016, 1020, 1022};
    #pragma unroll
    for (int li = 1; li < 4; ++li) {
        const int ns = 8 >> li;
        for (int j = grp; j < ns; j += 4) {
            float sk = cK[LB[li - 1] + 2 * j][col] + cK[LB[li - 1] + 2 * j + 1][col];
            float sv = cV[LB[li - 1] + 2 * j][col] + cV[LB[li - 1] + 2 * j + 1][col];
            cK[LB[li] + j][col] = sk; cV[LB[li] + j][col] = sv;
            size_t o = ((size_t)(GB[li] + j) * NHEAD + h) * 64 + col;
            float kv_ = sk + bk, vv_ = sv + bv;
            KsetH[o] = bf16_hi_trunc(kv_); KsetL[o] = bf16_lo_trunc(kv_);
            VsetB[o] = bf16_rne(vv_);
        }
        __syncthreads();
    }
}

// ---------- MFMA flash attention v9 (R9 state): 32-row tiles, single-buffered
// sS/sP, mask fast-path, early prefetch, bf16 tail-V ----------
__global__ __launch_bounds__(256, 3) void attn_mfma(
    const float* __restrict__ qbuf,
    const unsigned short* __restrict__ KsetH, const unsigned short* __restrict__ KsetL,
    const unsigned short* __restrict__ VsetB,
    const float* __restrict__ Ktail, const unsigned short* __restrict__ Vtb,
    _Float16* __restrict__ attf)
{
    __shared__ unsigned ssAll[1024];       // sid | (send<<16)
    __shared__ float sS[32][68];           // masked logits (pre-scaled)
    __shared__ unsigned sP[32][40];        // P as bf16 pairs along k
    __shared__ unsigned vP[2][64][40];     // V^T as bf16 pairs along set
    __shared__ float arowS[32];
    __shared__ float alS[32], ptS[32];

    const int tid = threadIdx.x;
    const int b   = 63 - (blockIdx.x / NHEAD);   // heavy blocks dispatched first
    const int h   = blockIdx.x % NHEAD;
    const int T0  = b * 32;
    const int wave = tid >> 6, lane = tid & 63;
    const int lane15 = lane & 15, quad = lane >> 4;

    const int Tend = T0 + 32;
    const int LOFF[10] = {0, 512, 768, 896, 960, 992, 1008, 1016, 1020, 1022};
    int pfx[10], Vtot = 0;
    #pragma unroll
    for (int li = 0; li < 10; ++li) { pfx[li] = Vtot; Vtot += Tend >> (li + 2); }
    const int ntiles = (Vtot + 63) >> 6;

    for (int j = tid; j < 1024; j += 256) {
        unsigned pk = (4095u << 16);       // send=4095 masks all rows; sid=0 harmless
        if (j < Vtot) {
            int li = 0;
            #pragma unroll
            for (int u = 1; u < 10; ++u) if (j >= pfx[u]) li = u;
            int idx = j - pfx[li];
            pk = (unsigned)(LOFF[li] + idx) | ((unsigned)((idx + 1) << (li + 2)) << 16);
        }
        ssAll[j] = pk;
    }

    short8 Qhi[2][2], Qlo[2][2];
    #pragma unroll
    for (int ms = 0; ms < 2; ++ms)
        #pragma unroll
        for (int kt = 0; kt < 2; ++kt) {
            const float* qp = qbuf + ((size_t)(T0 + ms * 16 + lane15) * NHEAD + h) * 64 + kt * 32 + quad * 8;
            float f[8];
            *(float4*)&f[0] = *(const float4*)qp;
            *(float4*)&f[4] = *(const float4*)(qp + 4);
            split8_bf16(f, Qhi[ms][kt], Qlo[ms][kt]);
        }

    __syncthreads();   // ssAll ready

    const int row = tid >> 3, part = tid & 7;
    float mreg = -1e30f, lreg = 0.f;

    f32x4 oacc[2];
    oacc[0] = (f32x4){0.f, 0.f, 0.f, 0.f};
    oacc[1] = (f32x4){0.f, 0.f, 0.f, 0.f};

    u16x8 Va, Vb;                  // V bf16: 8 dims of even/odd set
    u16x8 KH[2], KL[2];            // K bf16 hi/lo: dims quad*8..+7, +32
    const int sp = tid >> 3, dd = (tid & 7) * 8;
    auto prefV = [&](int tile) {
        int sa = (int)(ssAll[tile * 64 + 2 * sp] & 0xffffu);
        int sb = (int)(ssAll[tile * 64 + 2 * sp + 1] & 0xffffu);
        Va = *(const u16x8*)(VsetB + ((size_t)sa * NHEAD + h) * 64 + dd);
        Vb = *(const u16x8*)(VsetB + ((size_t)sb * NHEAD + h) * 64 + dd);
    };
    auto prefK = [&](int tile) {
        int sK = (int)(ssAll[tile * 64 + wave * 16 + lane15] & 0xffffu);
        const size_t ko = ((size_t)sK * NHEAD + h) * 64 + quad * 8;
        KH[0] = *(const u16x8*)(KsetH + ko);
        KH[1] = *(const u16x8*)(KsetH + ko + 32);
        KL[0] = *(const u16x8*)(KsetL + ko);
        KL[1] = *(const u16x8*)(KsetL + ko + 32);
    };
    prefV(0); prefK(0);

    for (int tile = 0; tile < ntiles; ++tile) {
        const int c = tile & 1;

        // stage V^T bf16 pairs (pure shift-or; other buffer than PV(t-1) reads)
        #pragma unroll
        for (int i = 0; i < 8; ++i)
            vP[c][dd + i][sp] = (unsigned)Va[i] | ((unsigned)Vb[i] << 16);

        // K fragments: direct reinterpret (pre-split)
        short8 Khi[2] = { as_s8(KH[0]), as_s8(KH[1]) };
        short8 Klo[2] = { as_s8(KL[0]), as_s8(KL[1]) };

        const int sendv = (int)(ssAll[tile * 64 + wave * 16 + lane15] >> 16);

        // issue prefetch for next tile EARLY (Va/Vb/KH/KL dead; loads gain
        // the QK-MFMA + mask window of latency cover)
        if (tile + 1 < ntiles) { prefV(tile + 1); prefK(tile + 1); }

        // QK^T 3-term split
        f32x4 lacc[2];
        lacc[0] = (f32x4){0.f, 0.f, 0.f, 0.f};
        lacc[1] = (f32x4){0.f, 0.f, 0.f, 0.f};
        #pragma unroll
        for (int kt = 0; kt < 2; ++kt)
            #pragma unroll
            for (int ms = 0; ms < 2; ++ms) {
                lacc[ms] = __builtin_amdgcn_mfma_f32_16x16x32_bf16(Qhi[ms][kt], Khi[kt], lacc[ms], 0, 0, 0);
                lacc[ms] = __builtin_amdgcn_mfma_f32_16x16x32_bf16(Qlo[ms][kt], Khi[kt], lacc[ms], 0, 0, 0);
                lacc[ms] = __builtin_amdgcn_mfma_f32_16x16x32_bf16(Qhi[ms][kt], Klo[kt], lacc[ms], 0, 0, 0);
            }

        // mask + scale (base-2 domain) -> sS; fast path if nothing masked
        if (!__any(sendv > T0 + 1)) {
            #pragma unroll
            for (int ms = 0; ms < 2; ++ms)
                #pragma unroll
                for (int r = 0; r < 4; ++r) {
                    int qrow = ms * 16 + quad * 4 + r;
                    sS[qrow][wave * 16 + lane15] = lacc[ms][r] * SOFTMAX_SCL;
                }
        } else {
            #pragma unroll
            for (int ms = 0; ms < 2; ++ms)
                #pragma unroll
                for (int r = 0; r < 4; ++r) {
                    int qrow = ms * 16 + quad * 4 + r;
                    bool ok = (T0 + qrow + 1) >= sendv;
                    sS[qrow][wave * 16 + lane15] = ok ? lacc[ms][r] * SOFTMAX_SCL : -1e30f;
                }
        }

        __syncthreads();   // B1: sS + vP[c] published; prior-tile PV complete

        // register softmax (base-2, guard-free)
        {
            float4 a = *(float4*)&sS[row][part * 8];
            float4 c4 = *(float4*)&sS[row][part * 8 + 4];
            float mx = fmaxf(fmaxf(fmaxf(a.x, a.y), fmaxf(a.z, a.w)),
                             fmaxf(fmaxf(c4.x, c4.y), fmaxf(c4.z, c4.w)));
            mx = fmaxf(mx, __shfl_xor(mx, 1));
            mx = fmaxf(mx, __shfl_xor(mx, 2));
            mx = fmaxf(mx, __shfl_xor(mx, 4));
            float mnew = fmaxf(mreg, mx);
            float al = exp2f(mreg - mnew);
            mreg = mnew;
            float mexp = fmaxf(mnew, -1e28f);
            a.x = exp2f(a.x - mexp);
            a.y = exp2f(a.y - mexp);
            a.z = exp2f(a.z - mexp);
            a.w = exp2f(a.w - mexp);
            c4.x = exp2f(c4.x - mexp);
            c4.y = exp2f(c4.y - mexp);
            c4.z = exp2f(c4.z - mexp);
            c4.w = exp2f(c4.w - mexp);
            float sm = (a.x + a.y + a.z + a.w) + (c4.x + c4.y + c4.z + c4.w);
            sm += __shfl_xor(sm, 1);
            sm += __shfl_xor(sm, 2);
            sm += __shfl_xor(sm, 4);
            lreg = al * lreg + sm;
            unsigned w0 = pack2_bf16_rne(a.x, a.y);
            unsigned w1 = pack2_bf16_rne(a.z, a.w);
            unsigned w2 = pack2_bf16_rne(c4.x, c4.y);
            unsigned w3 = pack2_bf16_rne(c4.z, c4.w);
            *(uint4*)&sP[row][part * 4] = make_uint4(w0, w1, w2, w3);
            if (part == 0) arowS[row] = al;
        }

        __syncthreads();   // B2: sP + arowS published

        // rescale + PV
        #pragma unroll
        for (int ms = 0; ms < 2; ++ms)
            #pragma unroll
            for (int r = 0; r < 4; ++r)
                oacc[ms][r] *= arowS[ms * 16 + quad * 4 + r];

        #pragma unroll
        for (int kt = 0; kt < 2; ++kt) {
            short8 Vf = *(short8*)&vP[c][wave * 16 + lane15][kt * 16 + quad * 4];
            #pragma unroll
            for (int ms = 0; ms < 2; ++ms) {
                short8 Pf = *(short8*)&sP[ms * 16 + lane15][kt * 16 + quad * 4];
                oacc[ms] = __builtin_amdgcn_mfma_f32_16x16x32_bf16(Pf, Vf, oacc[ms], 0, 0, 0);
            }
        }
    }

    // tail column (register state, base-2 domain)
    {
        const float* qr = qbuf  + ((size_t)(T0 + row) * NHEAD + h) * 64 + part * 8;
        const float* kr = Ktail + ((size_t)(T0 + row) * NHEAD + h) * 64 + part * 8;
        float4 qa = *(const float4*)qr, qb = *(const float4*)(qr + 4);
        float4 ka = *(const float4*)kr, kb = *(const float4*)(kr + 4);
        float dp = qa.x * ka.x + qa.y * ka.y + qa.z * ka.z + qa.w * ka.w
                 + qb.x * kb.x + qb.y * kb.y + qb.z * kb.z + qb.w * kb.w;
        dp += __shfl_xor(dp, 1);
        dp += __shfl_xor(dp, 2);
        dp += __shfl_xor(dp, 4);
        float tl = dp * SOFTMAX_SCL;
        float mf = fmaxf(mreg, tl);
        float al = exp2f(mreg - mf);
        float pt = exp2f(tl - mf);
        float lf = al * lreg + pt;
        float inv = 1.f / lf;
        if (part == 0) { alS[row] = al * inv; ptS[row] = pt * inv; }
    }
    __syncthreads();

    // final values -> sS (f32) for fragment transpose; tail V is bf16
    #pragma unroll
    for (int ms = 0; ms < 2; ++ms)
        #pragma unroll
        for (int r = 0; r < 4; ++r) {
            int qrow = ms * 16 + quad * 4 + r;
            int col = wave * 16 + lane15;
            size_t base = ((size_t)(T0 + qrow) * NHEAD + h) * 64 + col;
            float vt = __uint_as_float((unsigned)Vtb[base] << 16);
            sS[qrow][col] = oacc[ms][r] * alS[qrow] + ptS[qrow] * vt;
        }
    __syncthreads();

    // write single-f16 A-fragments (final GEMM layout) directly
    {
        const int kt = wave >> 1, msf = wave & 1;
        float f[8];
        *(float4*)&f[0] = *(const float4*)&sS[msf * 16 + lane15][kt * 32 + quad * 8];
        *(float4*)&f[4] = *(const float4*)&sS[msf * 16 + lane15][kt * 32 + quad * 8 + 4];
        const size_t frag = (size_t)(b * 2 + msf) * 24 + (2 * h + kt);
        *(half8*)&attf[(frag * 64 + lane) * 8] = cvt8_f16(f);
    }
}

extern "C" void kernel_launch(void* const* d_in, const int* in_sizes, int n_in,
                              void* d_out, int out_size, void* d_ws, size_t ws_size,
                              hipStream_t stream)
{
    const float* x   = (const float*)d_in[0];
    const float* Wq  = (const float*)d_in[1];
    const float* Wk  = (const float*)d_in[2];
    const float* Wv  = (const float*)d_in[3];
    const float* Wks = (const float*)d_in[4];
    const float* bks = (const float*)d_in[5];
    const float* Wvs = (const float*)d_in[6];
    const float* bvs = (const float*)d_in[7];
    const float* Wc  = (const float*)d_in[8];
    const float* bc  = (const float*)d_in[9];
    float* out = (float*)d_out;

    float* ws = (float*)d_ws;
    const size_t TC = (size_t)TLEN * CDIM;
    float* q      = ws;
    float* k      = q + TC;
    float* v      = k + TC;
    float* kkv    = v + TC;
    float* vvv    = kkv + TC;
    float* Kt     = vvv + TC;
    float* Vt     = Kt + TC;
    float* base   = Vt + TC;                      // blobs/scratch region
    _Float16* WblobMap = (_Float16*)base;
    _Float16* blobQKV  = (_Float16*)(base + 262144);
    float* scrK = base + 1146880;
    float* scrV = scrK + 12 * 16 * 64;
    _Float16* blobC = (_Float16*)(base + 1171456);
    unsigned short* KsetH = (unsigned short*)(base + 1466368);
    unsigned short* KsetL = KsetH + 786432;
    unsigned short* VsetB = KsetL + 786432;
    // x f16 fragment blob: alias kkv region; dead before map_f16 writes kkv
    _Float16* xf = (_Float16*)kkv;
    // kkv/vvv as f16 (map output, set input)
    _Float16* kkv16 = (_Float16*)kkv;
    _Float16* vvv16 = (_Float16*)vvv;
    // k as dup-packed u32, v as f16: alias k / v regions
    unsigned*  kdup = (unsigned*)k;
    _Float16*  v16  = (_Float16*)v;
    // tail V as bf16: alias Vt region (half the bytes)
    unsigned short* Vtb = (unsigned short*)Vt;
    // attn output fragments: alias vvv region (vvv dead after set_lower)
    _Float16* attf = (_Float16*)vvv;

    prep_all<<<1152 + 256 + 768, 256, 0, stream>>>(
        Wq, Wk, Wv, Wc, Wks, Wvs, x, blobQKV, blobC, WblobMap, xf);

    gemm_frag<1><<<576, 256, 0, stream>>>(xf, blobQKV, nullptr, q, kdup, v16);

    map_f16<<<(TLEN * NHEAD) / 64, 256, 0, stream>>>(kdup, v16, WblobMap, kkv16, vvv16);

    set_lower<<<16 * NHEAD, 256, 0, stream>>>(kkv16, vvv16, bks, bvs, KsetH, KsetL, VsetB, scrK, scrV, Kt, Vtb);
    set_upper<<<NHEAD, 256, 0, stream>>>(scrK, scrV, bks, bvs, KsetH, KsetL, VsetB);

    attn_mfma<<<(TLEN / 32) * NHEAD, 256, 0, stream>>>(q, KsetH, KsetL, VsetB, Kt, Vtb, attf);

    gemm_frag<0><<<384, 256, 0, stream>>>(attf, blobC, bc, out, nullptr, nullptr);
}